// Round 7
// baseline (441.498 us; speedup 1.0000x reference)
//
#include <hip/hip_runtime.h>

#define N_NODES 10000
#define N_EDGES 160000
#define NTILES   10000              // E/16 exactly (160000 % 16 == 0), packed CSR
#define MSG_GRID 2500               // x4 strided tiles = 10000
#define PHI_BLOCKS 628
#define RC_BLOCKS 5000              // E*8 / 256

typedef __attribute__((ext_vector_type(8))) __bf16 bf16x8;
typedef __attribute__((ext_vector_type(8))) unsigned short u16x8;
typedef __attribute__((ext_vector_type(4))) float f32x4;

static __device__ __forceinline__ unsigned short f2bf(float x) {
    union { float f; unsigned u; } un;
    un.f = x;
    unsigned r = un.u + 0x7fffu + ((un.u >> 16) & 1u);  // RNE
    return (unsigned short)(r >> 16);
}

static __device__ __forceinline__ float bf2f(unsigned short h) {
    union { unsigned u; float f; } un;
    un.u = ((unsigned)h) << 16;
    return un.f;
}

// ---------------------------------------------------------------------------
// Fused init: float4 copies, weight transpose->bf16, vbf2 packing, degree
// histogram. Grid = 5000x256.
// ---------------------------------------------------------------------------
__global__ __launch_bounds__(256) void init_kernel(
    const float* __restrict__ s, const float* __restrict__ v,
    const int* __restrict__ eix,
    const float* __restrict__ W1, const float* __restrict__ W2,
    const float* __restrict__ Wr,
    float* __restrict__ out0, float* __restrict__ out1,
    unsigned short* __restrict__ vbf2, int* __restrict__ cnt,
    unsigned short* __restrict__ W1T, unsigned short* __restrict__ W2T,
    unsigned short* __restrict__ WrT)
{
    int tid = blockIdx.x * 256 + threadIdx.x;
    if (tid < N_NODES * 96)                      // out1 = v, float4
        reinterpret_cast<float4*>(out1)[tid] = reinterpret_cast<const float4*>(v)[tid];
    if (tid < N_NODES * 32)                      // out0 = s, float4
        reinterpret_cast<float4*>(out0)[tid] = reinterpret_cast<const float4*>(s)[tid];
    if (tid < N_NODES * 128) {                   // vbf2[n][f] = {vx,vy,vz,0} bf16
        int n = tid >> 7, f = tid & 127;
        ushort4 q;
        q.x = f2bf(v[(size_t)n * 384 + f]);
        q.y = f2bf(v[(size_t)n * 384 + 128 + f]);
        q.z = f2bf(v[(size_t)n * 384 + 256 + f]);
        q.w = 0;
        *reinterpret_cast<ushort4*>(vbf2 + (size_t)tid * 4) = q;
    }
    if (tid < 131072) {                          // W2T [1024][128]
        int n = tid >> 7, k = tid & 127;
        W2T[tid] = f2bf(W2[k * 1024 + n]);
    }
    if (tid < 16384) {                           // W1T [128][128]
        int n = tid >> 7, k = tid & 127;
        W1T[tid] = f2bf(W1[k * 128 + n]);
    }
    if (tid < 32768) {                           // WrT [1024][32]
        int n = tid >> 5, k = tid & 31;
        WrT[tid] = f2bf(Wr[k * 1024 + n]);
    }
    if (tid < N_EDGES) atomicAdd(&cnt[eix[tid]], 1);
}

// ---------------------------------------------------------------------------
// Fused scan + phi. Blocks [0, PHI_BLOCKS) = phi; block PHI_BLOCKS = one-block
// degree prefix-scan (packed CSR: cursor[n] = exclusive prefix of deg) hidden
// under phi.
// ---------------------------------------------------------------------------
__global__ __launch_bounds__(256) void scan_phi_kernel(
    const int* __restrict__ cnt, int* __restrict__ cursor,
    const float* __restrict__ s, const unsigned short* __restrict__ W1T,
    const float* __restrict__ b1, const unsigned short* __restrict__ W2T,
    const float* __restrict__ b2, unsigned short* __restrict__ phi2)
{
    __shared__ unsigned short h_lds[64][136];
    __shared__ int ws4[4];
    int bx = blockIdx.x;
    int t = threadIdx.x, lane = t & 63, w = t >> 6;

    if (bx == PHI_BLOCKS) {
        // ---------------- scan: 256 threads x 40 nodes, prefix of DEGREES ---
        int n0 = t * 40;
        int sum = 0;
        for (int i = 0; i < 40; ++i) {
            int n = n0 + i;
            if (n < N_NODES) sum += cnt[n];
        }
        int x = sum;
        #pragma unroll
        for (int o = 1; o < 64; o <<= 1) {
            int y = __shfl_up(x, o);
            if (lane >= o) x += y;
        }
        if (lane == 63) ws4[w] = x;
        __syncthreads();
        if (t < 4) {
            int vsum = ws4[t];
            #pragma unroll
            for (int o = 1; o < 4; o <<= 1) {
                int y = __shfl_up(vsum, o);
                if (lane >= o) vsum += y;
            }
            ws4[t] = vsum;               // inclusive wave sums
        }
        __syncthreads();
        int wb = w ? ws4[w - 1] : 0;
        int run = wb + x - sum;          // exclusive prefix (edge slots)
        for (int i = 0; i < 40; ++i) {
            int n = n0 + i;
            if (n >= N_NODES) break;
            cursor[n] = run;
            run += cnt[n];
        }
        return;
    }

    // ---------------- phi: silu(s@W1+b1)@W2+b2 ----------------
    int quad = lane >> 4, l16 = lane & 15;
    int m0 = (bx >> 2) * 64;
    int colg = bx & 3;

    int arow = m0 + w * 16 + l16;
    if (arow > N_NODES - 1) arow = N_NODES - 1;
    bf16x8 afr[4];
    #pragma unroll
    for (int ks = 0; ks < 4; ++ks) {
        const float* sp = s + (size_t)arow * 128 + ks * 32 + quad * 8;
        #pragma unroll
        for (int jj = 0; jj < 8; ++jj) afr[ks][jj] = (__bf16)sp[jj];
    }
    #pragma unroll
    for (int cg = 0; cg < 8; ++cg) {
        int col = cg * 16 + l16;
        f32x4 acc = {0.f, 0.f, 0.f, 0.f};
        #pragma unroll
        for (int ks = 0; ks < 4; ++ks) {
            bf16x8 bf = *reinterpret_cast<const bf16x8*>(W1T + (size_t)col * 128 + ks * 32 + quad * 8);
            acc = __builtin_amdgcn_mfma_f32_16x16x32_bf16(afr[ks], bf, acc, 0, 0, 0);
        }
        float bb = b1[col];
        #pragma unroll
        for (int r = 0; r < 4; ++r) {
            int row = w * 16 + quad * 4 + r;
            float val = acc[r] + bb;
            h_lds[row][col] = f2bf(val / (1.f + __expf(-val)));
        }
    }
    __syncthreads();

    bf16x8 a2[4][4];
    #pragma unroll
    for (int rg = 0; rg < 4; ++rg)
        #pragma unroll
        for (int ks = 0; ks < 4; ++ks)
            a2[rg][ks] = *reinterpret_cast<const bf16x8*>(&h_lds[rg * 16 + l16][ks * 32 + quad * 8]);
    #pragma unroll
    for (int i = 0; i < 4; ++i) {
        int col = colg * 256 + w * 64 + i * 16 + l16;
        f32x4 acc2[4] = {{0,0,0,0},{0,0,0,0},{0,0,0,0},{0,0,0,0}};
        #pragma unroll
        for (int ks = 0; ks < 4; ++ks) {
            bf16x8 bf = *reinterpret_cast<const bf16x8*>(W2T + (size_t)col * 128 + ks * 32 + quad * 8);
            #pragma unroll
            for (int rg = 0; rg < 4; ++rg)
                acc2[rg] = __builtin_amdgcn_mfma_f32_16x16x32_bf16(a2[rg][ks], bf, acc2[rg], 0, 0, 0);
        }
        float bb = b2[col];
        int f = col & 127, cc = col >> 7;
        #pragma unroll
        for (int rg = 0; rg < 4; ++rg)
            #pragma unroll
            for (int r = 0; r < 4; ++r) {
                int row = m0 + rg * 16 + quad * 4 + r;
                if (row < N_NODES)
                    phi2[(size_t)row * 1024 + f * 8 + cc] = f2bf(acc2[rg][r] + bb);
            }
    }
}

// ---------------------------------------------------------------------------
// rc on the 128-B interleaved record at PACKED CSR slots:
// rec[slot] = {Rc 32xushort | hdr 16xfloat: j, fsum, node, -, u1xyz-, u2xyz-, u3xyz-}
// No pad pass (CSR fully packed, E % 16 == 0).
// ---------------------------------------------------------------------------
__global__ __launch_bounds__(256) void rc_kernel(
    const float* __restrict__ R1, const float* __restrict__ R2,
    const float* __restrict__ R3,
    const float* __restrict__ f1, const float* __restrict__ f2,
    const float* __restrict__ f3,
    const float* __restrict__ u1, const float* __restrict__ u2,
    const float* __restrict__ u3,
    const int* __restrict__ eix, int* __restrict__ cursor,
    char* __restrict__ rec)
{
    int tid = blockIdx.x * 256 + threadIdx.x;    // exactly E*8 threads
    int e = tid >> 3, sub = tid & 7;
    int lane = threadIdx.x & 63;
    float a = f1[e], b = f2[e], c = f3[e];
    int k0 = sub * 4;
    float4 r1 = *reinterpret_cast<const float4*>(R1 + (size_t)e * 32 + k0);
    float4 r2 = *reinterpret_cast<const float4*>(R2 + (size_t)e * 32 + k0);
    float4 r3 = *reinterpret_cast<const float4*>(R3 + (size_t)e * 32 + k0);
    ushort4 o;
    o.x = f2bf(r1.x * a + r2.x * b + r3.x * c);
    o.y = f2bf(r1.y * a + r2.y * b + r3.y * c);
    o.z = f2bf(r1.z * a + r2.z * b + r3.z * c);
    o.w = f2bf(r1.w * a + r2.w * b + r3.w * c);
    int slot = 0, node = 0;
    if (sub == 0) {
        node = eix[e];
        slot = atomicAdd(&cursor[node], 1);
    }
    slot = __shfl(slot, lane & 56);              // broadcast from sub0
    *reinterpret_cast<ushort4*>(rec + (size_t)slot * 128 + k0 * 2) = o;
    float* hf = reinterpret_cast<float*>(rec + (size_t)slot * 128 + 64);
    if (sub == 0) {
        float4 h;
        h.x = __int_as_float(eix[N_EDGES + e]);  // j
        h.y = a + b + c;                         // fsum
        h.z = __int_as_float(node);              // destination node (for seg-reduce)
        h.w = 0.f;
        *reinterpret_cast<float4*>(hf) = h;
    } else if (sub < 4) {
        const float* up = (sub == 1 ? u1 : (sub == 2 ? u2 : u3)) + (size_t)e * 3;
        float4 h;
        h.x = up[0]; h.y = up[1]; h.z = up[2]; h.w = 0.f;
        *reinterpret_cast<float4*>(hf + sub * 4) = h;
    }
}

// ---------------------------------------------------------------------------
// Main msg kernel: PACKED tiles (16 consecutive CSR slots, may span nodes).
// Segmented reduction: node id per row from hdr; each thread accumulates its
// 4 contiguous rows, flushing on node change; each quad flushes its pending
// segment via atomics (replaces the cross-quad shfl reduce). i-sorted CSR ->
// segments are runs; node checks are quad-uniform.
// ---------------------------------------------------------------------------
__global__ __launch_bounds__(512) void msg_kernel(
    const char* __restrict__ rec,
    const unsigned short* __restrict__ phi2, const unsigned short* __restrict__ vbf2,
    const unsigned short* __restrict__ WrT, const float* __restrict__ br,
    float* __restrict__ out0, float* __restrict__ out1)
{
    int t = threadIdx.x, lane = t & 63, w = t >> 6;
    int quad = lane >> 4, l16 = lane & 15;
    int fcol = w * 16 + l16;
    const float* recf = reinterpret_cast<const float*>(rec);

    bf16x8 bfrag[8];
    float brv[8];
    #pragma unroll
    for (int c = 0; c < 8; ++c) {
        int col = c * 128 + fcol;
        bfrag[c] = *reinterpret_cast<const bf16x8*>(WrT + (size_t)col * 32 + quad * 8);
        brv[c] = br[col];
    }

    __shared__ __align__(16) float srow[2][16][20];  // [j,fs,nd,-|u1 -,|u2 -,|u3 -,pad]

    int tile = blockIdx.x;
    bf16x8 af;
    {
        if (t < 256)
            srow[0][t >> 4][t & 15] = recf[((size_t)tile * 16 + (t >> 4)) * 32 + 16 + (t & 15)];
        af = *reinterpret_cast<const bf16x8*>(rec + ((size_t)tile * 16 + l16) * 128 + quad * 16);
    }

    for (int k = 0; k < 4; ++k, tile += MSG_GRID) {
        int p = k & 1;
        __syncthreads();   // publishes srow[p]; reads of srow[p^1] all done

        f32x4 acc[8];
        #pragma unroll
        for (int c = 0; c < 8; ++c) {
            f32x4 z = {0.f, 0.f, 0.f, 0.f};
            acc[c] = __builtin_amdgcn_mfma_f32_16x16x32_bf16(af, bfrag[c], z, 0, 0, 0);
        }

        // stage NEXT tile (header -> srow[p^1], A-frag -> af) under the epilogue
        int tn = tile + MSG_GRID;
        if (tn < NTILES) {
            if (t < 256)
                srow[p ^ 1][t >> 4][t & 15] = recf[((size_t)tn * 16 + (t >> 4)) * 32 + 16 + (t & 15)];
            af = *reinterpret_cast<const bf16x8*>(rec + ((size_t)tn * 16 + l16) * 128 + quad * 16);
        }

        float ds = 0.f, d0 = 0.f, d1 = 0.f, d2 = 0.f;
        int cur = __float_as_int(srow[p][quad * 4][2]);
        #pragma unroll
        for (int r = 0; r < 4; ++r) {
            const float* rw = srow[p][quad * 4 + r];
            f32x4 h0 = *reinterpret_cast<const f32x4*>(rw);
            f32x4 U1 = *reinterpret_cast<const f32x4*>(rw + 4);
            f32x4 U2 = *reinterpret_cast<const f32x4*>(rw + 8);
            f32x4 U3 = *reinterpret_cast<const f32x4*>(rw + 12);
            int ndr = __float_as_int(h0.z);
            if (ndr != cur) {                     // quad-uniform branch
                atomicAdd(&out0[(size_t)cur * 128 + fcol], ds);
                size_t vo = (size_t)cur * 384 + fcol;
                atomicAdd(&out1[vo], d0);
                atomicAdd(&out1[vo + 128], d1);
                atomicAdd(&out1[vo + 256], d2);
                cur = ndr; ds = 0.f; d0 = 0.f; d1 = 0.f; d2 = 0.f;
            }
            int j = __float_as_int(h0.x);
            float fs = h0.y;
            size_t o = (size_t)j * 128 + fcol;
            u16x8 ph = *reinterpret_cast<const u16x8*>(phi2 + o * 8);
            ushort4 vb = *reinterpret_cast<const ushort4*>(vbf2 + o * 4);
            float x[8];
            #pragma unroll
            for (int c = 0; c < 8; ++c)
                x[c] = bf2f(ph[c]) * (acc[c][r] + brv[c] * fs);
            float vjx = bf2f(vb.x), vjy = bf2f(vb.y), vjz = bf2f(vb.z);

            ds += x[0];
            d0 += vjx * x[1] + U1.x * x[2] + U2.x * x[3] + U3.x * x[4]
                + x[5] * (vjy * U1.z - vjz * U1.y)
                + x[6] * (vjy * U2.z - vjz * U2.y)
                + x[7] * (vjy * U3.z - vjz * U3.y);
            d1 += vjy * x[1] + U1.y * x[2] + U2.y * x[3] + U3.y * x[4]
                + x[5] * (vjz * U1.x - vjx * U1.z)
                + x[6] * (vjz * U2.x - vjx * U2.z)
                + x[7] * (vjz * U3.x - vjx * U3.z);
            d2 += vjz * x[1] + U1.z * x[2] + U2.z * x[3] + U3.z * x[4]
                + x[5] * (vjx * U1.y - vjy * U1.x)
                + x[6] * (vjx * U2.y - vjy * U2.x)
                + x[7] * (vjx * U3.y - vjy * U3.x);
        }
        // flush pending segment
        atomicAdd(&out0[(size_t)cur * 128 + fcol], ds);
        size_t vo = (size_t)cur * 384 + fcol;
        atomicAdd(&out1[vo], d0);
        atomicAdd(&out1[vo + 128], d1);
        atomicAdd(&out1[vo + 256], d2);
    }
}

// ---------------------------------------------------------------------------
extern "C" void kernel_launch(void* const* d_in, const int* in_sizes, int n_in,
                              void* d_out, int out_size, void* d_ws, size_t ws_size,
                              hipStream_t stream) {
    const float* s  = (const float*)d_in[0];
    const float* v  = (const float*)d_in[1];
    const float* R1 = (const float*)d_in[2];
    const float* R2 = (const float*)d_in[3];
    const float* R3 = (const float*)d_in[4];
    const float* f1 = (const float*)d_in[5];
    const float* f2 = (const float*)d_in[6];
    const float* f3 = (const float*)d_in[7];
    const float* u1 = (const float*)d_in[8];
    const float* u2 = (const float*)d_in[9];
    const float* u3 = (const float*)d_in[10];
    const int*  eix = (const int*)d_in[11];
    const float* W1 = (const float*)d_in[12];
    const float* b1 = (const float*)d_in[13];
    const float* W2 = (const float*)d_in[14];
    const float* b2 = (const float*)d_in[15];
    const float* Wr = (const float*)d_in[16];
    const float* br = (const float*)d_in[17];

    char* ws = (char*)d_ws;
    size_t off = 0;
    auto alloc = [&](size_t bytes) -> void* {
        void* p = ws + off;
        off = (off + bytes + 255) & ~(size_t)255;
        return p;
    };
    int* cnt       = (int*)alloc((size_t)N_NODES * 4);
    int* cursor    = (int*)alloc((size_t)N_NODES * 4);
    char* rec            = (char*)alloc((size_t)N_EDGES * 128);
    unsigned short* vbf2 = (unsigned short*)alloc((size_t)N_NODES * 128 * 4 * 2);
    unsigned short* phi2 = (unsigned short*)alloc((size_t)N_NODES * 1024 * 2);
    unsigned short* W1T  = (unsigned short*)alloc(128 * 128 * 2);
    unsigned short* W2T  = (unsigned short*)alloc(1024 * 128 * 2);
    unsigned short* WrT  = (unsigned short*)alloc(1024 * 32 * 2);
    (void)ws_size; (void)in_sizes; (void)n_in; (void)out_size;

    float* out0 = (float*)d_out;
    float* out1 = out0 + (size_t)N_NODES * 128;

    hipMemsetAsync(cnt, 0, (size_t)N_NODES * 4, stream);
    init_kernel<<<5000, 256, 0, stream>>>(s, v, eix, W1, W2, Wr,
                                          out0, out1, vbf2, cnt, W1T, W2T, WrT);
    scan_phi_kernel<<<PHI_BLOCKS + 1, 256, 0, stream>>>(
        cnt, cursor, s, W1T, b1, W2T, b2, phi2);
    rc_kernel<<<RC_BLOCKS, 256, 0, stream>>>(
        R1, R2, R3, f1, f2, f3, u1, u2, u3, eix, cursor, rec);
    msg_kernel<<<MSG_GRID, 512, 0, stream>>>(rec, phi2, vbf2, WrT, br, out0, out1);
}

// Round 10
// 386.713 us; speedup vs baseline: 1.1417x; 1.1417x over previous
//
#include <hip/hip_runtime.h>

#define N_NODES 10000
#define N_EDGES 160000
#define MAXT     19400              // >= sum(ceil(deg/16)) <= (E + 15N)/16 = 19375
#define NSLOT    (MAXT * 16 + 16)   // 16-aligned CSR slots + guard
#define MSG_GRID 5000               // x4 strided tiles = 20000 slots
#define PHI_BLOCKS 628
#define RC_BLOCKS 5000              // E*8 / 256
#define PAD_BLOCKS 625              // N*16 / 256

typedef __attribute__((ext_vector_type(8))) __bf16 bf16x8;
typedef __attribute__((ext_vector_type(8))) unsigned short u16x8;
typedef __attribute__((ext_vector_type(4))) float f32x4;

static __device__ __forceinline__ unsigned short f2bf(float x) {
    union { float f; unsigned u; } un;
    un.f = x;
    unsigned r = un.u + 0x7fffu + ((un.u >> 16) & 1u);  // RNE
    return (unsigned short)(r >> 16);
}

static __device__ __forceinline__ float bf2f(unsigned short h) {
    union { unsigned u; float f; } un;
    un.u = ((unsigned)h) << 16;
    return un.f;
}

// perm within a 16-slot tile: edge k -> slot ((k&3)<<2)|(k>>2). Self-inverse.
// Puts edge 4r+q at slot 4q+r, so MFMA reg r / quad q <-> edge 4r+q and the
// epilogue's iteration r covers edges 4r..4r+3 (wave-uniform skip of pads).
static __device__ __forceinline__ int tperm(int o) {
    return ((o & 3) << 2) | (o >> 2);
}

// ---------------------------------------------------------------------------
// Fused init: float4 copies, weight transpose->bf16, vbf2 packing, degree
// histogram. Grid = 5000x256.
// ---------------------------------------------------------------------------
__global__ __launch_bounds__(256) void init_kernel(
    const float* __restrict__ s, const float* __restrict__ v,
    const int* __restrict__ eix,
    const float* __restrict__ W1, const float* __restrict__ W2,
    const float* __restrict__ Wr,
    float* __restrict__ out0, float* __restrict__ out1,
    unsigned short* __restrict__ vbf2, int* __restrict__ cnt,
    unsigned short* __restrict__ W1T, unsigned short* __restrict__ W2T,
    unsigned short* __restrict__ WrT)
{
    int tid = blockIdx.x * 256 + threadIdx.x;
    if (tid < N_NODES * 96)                      // out1 = v, float4
        reinterpret_cast<float4*>(out1)[tid] = reinterpret_cast<const float4*>(v)[tid];
    if (tid < N_NODES * 32)                      // out0 = s, float4
        reinterpret_cast<float4*>(out0)[tid] = reinterpret_cast<const float4*>(s)[tid];
    if (tid < N_NODES * 128) {                   // vbf2[n][f] = {vx,vy,vz,0} bf16
        int n = tid >> 7, f = tid & 127;
        ushort4 q;
        q.x = f2bf(v[(size_t)n * 384 + f]);
        q.y = f2bf(v[(size_t)n * 384 + 128 + f]);
        q.z = f2bf(v[(size_t)n * 384 + 256 + f]);
        q.w = 0;
        *reinterpret_cast<ushort4*>(vbf2 + (size_t)tid * 4) = q;
    }
    if (tid < 131072) {                          // W2T [1024][128]
        int n = tid >> 7, k = tid & 127;
        W2T[tid] = f2bf(W2[k * 1024 + n]);
    }
    if (tid < 16384) {                           // W1T [128][128]
        int n = tid >> 7, k = tid & 127;
        W1T[tid] = f2bf(W1[k * 128 + n]);
    }
    if (tid < 32768) {                           // WrT [1024][32]
        int n = tid >> 5, k = tid & 31;
        WrT[tid] = f2bf(Wr[k * 1024 + n]);
    }
    if (tid < N_EDGES) atomicAdd(&cnt[eix[tid]], 1);
}

// ---------------------------------------------------------------------------
// Fused scan + phi. Blocks [0, PHI_BLOCKS) = phi; block PHI_BLOCKS = one-block
// scan hidden under phi. tile_node packs node | (rows_in_tile << 16).
// ---------------------------------------------------------------------------
__global__ __launch_bounds__(256) void scan_phi_kernel(
    const int* __restrict__ cnt, int* __restrict__ cursor,
    int* __restrict__ nb, int* __restrict__ tile_node,
    int* __restrict__ ntiles,
    const float* __restrict__ s, const unsigned short* __restrict__ W1T,
    const float* __restrict__ b1, const unsigned short* __restrict__ W2T,
    const float* __restrict__ b2, unsigned short* __restrict__ phi2)
{
    __shared__ unsigned short h_lds[64][136];
    __shared__ int ws4[4];
    int bx = blockIdx.x;
    int t = threadIdx.x, lane = t & 63, w = t >> 6;

    if (bx == PHI_BLOCKS) {
        // ---------------- scan: 256 threads x 40 nodes ----------------
        int n0 = t * 40;
        int sum = 0;
        for (int i = 0; i < 40; ++i) {
            int n = n0 + i;
            if (n < N_NODES) sum += (cnt[n] + 15) >> 4;
        }
        int x = sum;
        #pragma unroll
        for (int o = 1; o < 64; o <<= 1) {
            int y = __shfl_up(x, o);
            if (lane >= o) x += y;
        }
        if (lane == 63) ws4[w] = x;
        __syncthreads();
        if (t < 4) {
            int vsum = ws4[t];
            #pragma unroll
            for (int o = 1; o < 4; o <<= 1) {
                int y = __shfl_up(vsum, o);
                if (lane >= o) vsum += y;
            }
            ws4[t] = vsum;               // inclusive wave sums
        }
        __syncthreads();
        int wb = w ? ws4[w - 1] : 0;
        int run = wb + x - sum;          // exclusive prefix, tile units
        for (int i = 0; i < 40; ++i) {
            int n = n0 + i;
            if (n >= N_NODES) break;
            int deg = cnt[n];
            int tc = (deg + 15) >> 4;
            nb[n] = run * 16;
            cursor[n] = run * 16;
            for (int k = 0; k < tc; ++k) {
                int rows = deg - k * 16;
                if (rows > 16) rows = 16;
                tile_node[run + k] = n | (rows << 16);
            }
            run += tc;
        }
        if (t == 255) *ntiles = run;
        return;
    }

    // ---------------- phi: silu(s@W1+b1)@W2+b2 ----------------
    int quad = lane >> 4, l16 = lane & 15;
    int m0 = (bx >> 2) * 64;
    int colg = bx & 3;

    int arow = m0 + w * 16 + l16;
    if (arow > N_NODES - 1) arow = N_NODES - 1;
    bf16x8 afr[4];
    #pragma unroll
    for (int ks = 0; ks < 4; ++ks) {
        const float* sp = s + (size_t)arow * 128 + ks * 32 + quad * 8;
        #pragma unroll
        for (int jj = 0; jj < 8; ++jj) afr[ks][jj] = (__bf16)sp[jj];
    }
    #pragma unroll
    for (int cg = 0; cg < 8; ++cg) {
        int col = cg * 16 + l16;
        f32x4 acc = {0.f, 0.f, 0.f, 0.f};
        #pragma unroll
        for (int ks = 0; ks < 4; ++ks) {
            bf16x8 bf = *reinterpret_cast<const bf16x8*>(W1T + (size_t)col * 128 + ks * 32 + quad * 8);
            acc = __builtin_amdgcn_mfma_f32_16x16x32_bf16(afr[ks], bf, acc, 0, 0, 0);
        }
        float bb = b1[col];
        #pragma unroll
        for (int r = 0; r < 4; ++r) {
            int row = w * 16 + quad * 4 + r;
            float val = acc[r] + bb;
            h_lds[row][col] = f2bf(val / (1.f + __expf(-val)));
        }
    }
    __syncthreads();

    bf16x8 a2[4][4];
    #pragma unroll
    for (int rg = 0; rg < 4; ++rg)
        #pragma unroll
        for (int ks = 0; ks < 4; ++ks)
            a2[rg][ks] = *reinterpret_cast<const bf16x8*>(&h_lds[rg * 16 + l16][ks * 32 + quad * 8]);
    #pragma unroll
    for (int i = 0; i < 4; ++i) {
        int col = colg * 256 + w * 64 + i * 16 + l16;
        f32x4 acc2[4] = {{0,0,0,0},{0,0,0,0},{0,0,0,0},{0,0,0,0}};
        #pragma unroll
        for (int ks = 0; ks < 4; ++ks) {
            bf16x8 bf = *reinterpret_cast<const bf16x8*>(W2T + (size_t)col * 128 + ks * 32 + quad * 8);
            #pragma unroll
            for (int rg = 0; rg < 4; ++rg)
                acc2[rg] = __builtin_amdgcn_mfma_f32_16x16x32_bf16(a2[rg][ks], bf, acc2[rg], 0, 0, 0);
        }
        float bb = b2[col];
        int f = col & 127, cc = col >> 7;
        #pragma unroll
        for (int rg = 0; rg < 4; ++rg)
            #pragma unroll
            for (int r = 0; r < 4; ++r) {
                int row = m0 + rg * 16 + quad * 4 + r;
                if (row < N_NODES)
                    phi2[(size_t)row * 1024 + f * 8 + cc] = f2bf(acc2[rg][r] + bb);
            }
    }
}

// ---------------------------------------------------------------------------
// rc + pad on the 128-B interleaved record, rows BIT-PERMUTED within tiles.
//  blocks [0, RC_BLOCKS):      per-edge Rc/hdr at permuted CSR slot
//  blocks [RC_BLOCKS, +PAD):   zero pad slots (permuted positions)
// ---------------------------------------------------------------------------
__global__ __launch_bounds__(256) void rc_pad_kernel(
    const float* __restrict__ R1, const float* __restrict__ R2,
    const float* __restrict__ R3,
    const float* __restrict__ f1, const float* __restrict__ f2,
    const float* __restrict__ f3,
    const float* __restrict__ u1, const float* __restrict__ u2,
    const float* __restrict__ u3,
    const int* __restrict__ eix, const int* __restrict__ cnt,
    const int* __restrict__ nb, int* __restrict__ cursor,
    char* __restrict__ rec)
{
    int bx = blockIdx.x;
    if (bx >= RC_BLOCKS) {
        // ---------------- pad: zero unused slots (full 128B record) -------
        int t2 = (bx - RC_BLOCKS) * 256 + threadIdx.x;   // [0, 16N)
        int n = t2 >> 4, r = t2 & 15;
        int deg = cnt[n], tc = (deg + 15) >> 4;
        int p = deg + r;
        if (p < tc * 16) {
            size_t lin = (size_t)nb[n] + p;              // nb 16-aligned
            size_t slot = (lin & ~(size_t)15) | tperm((int)(lin & 15));
            f32x4 z = {0.f, 0.f, 0.f, 0.f};
            f32x4* rp = reinterpret_cast<f32x4*>(rec + slot * 128);
            #pragma unroll
            for (int q = 0; q < 8; ++q) rp[q] = z;
        }
        return;
    }

    // ---------------- rc: Rc + packed header at permuted CSR slot ---------
    int tid = bx * 256 + threadIdx.x;            // exactly E*8 threads
    int e = tid >> 3, sub = tid & 7;
    int lane = threadIdx.x & 63;
    float a = f1[e], b = f2[e], c = f3[e];
    int k0 = sub * 4;
    float4 r1 = *reinterpret_cast<const float4*>(R1 + (size_t)e * 32 + k0);
    float4 r2 = *reinterpret_cast<const float4*>(R2 + (size_t)e * 32 + k0);
    float4 r3 = *reinterpret_cast<const float4*>(R3 + (size_t)e * 32 + k0);
    ushort4 o;
    o.x = f2bf(r1.x * a + r2.x * b + r3.x * c);
    o.y = f2bf(r1.y * a + r2.y * b + r3.y * c);
    o.z = f2bf(r1.z * a + r2.z * b + r3.z * c);
    o.w = f2bf(r1.w * a + r2.w * b + r3.w * c);
    int slot = 0;
    if (sub == 0) slot = atomicAdd(&cursor[eix[e]], 1);
    slot = __shfl(slot, lane & 56);              // broadcast from sub0
    size_t ps = ((size_t)slot & ~(size_t)15) | tperm(slot & 15);
    *reinterpret_cast<ushort4*>(rec + ps * 128 + k0 * 2) = o;
    float* hf = reinterpret_cast<float*>(rec + ps * 128 + 64);
    if (sub == 0) {
        float4 h;
        h.x = __int_as_float(eix[N_EDGES + e]);  // j
        h.y = a + b + c;                         // fsum
        h.z = 0.f; h.w = 0.f;
        *reinterpret_cast<float4*>(hf) = h;
    } else if (sub < 4) {
        const float* up = (sub == 1 ? u1 : (sub == 2 ? u2 : u3)) + (size_t)e * 3;
        float4 h;
        h.x = up[0]; h.y = up[1]; h.z = up[2]; h.w = 0.f;
        *reinterpret_cast<float4*>(hf + sub * 4) = h;
    }
}

// ---------------------------------------------------------------------------
// Main msg kernel: r6 double-buffer pipeline + wave-uniform skip of padded
// row-quads (rows bit-permuted so iteration r covers edges 4r..4r+3; loop
// bound nr = ceil(rows/4) from tile_node's upper bits, held in SGPR via
// readfirstlane so VGPR count stays at 64).
// ---------------------------------------------------------------------------
__global__ __launch_bounds__(512) void msg_kernel(
    const char* __restrict__ rec,
    const unsigned short* __restrict__ phi2, const unsigned short* __restrict__ vbf2,
    const unsigned short* __restrict__ WrT, const float* __restrict__ br,
    const int* __restrict__ tile_node, const int* __restrict__ ntiles,
    float* __restrict__ out0, float* __restrict__ out1)
{
    int t = threadIdx.x, lane = t & 63, w = t >> 6;
    int quad = lane >> 4, l16 = lane & 15;
    int fcol = w * 16 + l16;
    const int nt = *ntiles;
    const float* recf = reinterpret_cast<const float*>(rec);

    bf16x8 bfrag[8];
    float brv[8];
    #pragma unroll
    for (int c = 0; c < 8; ++c) {
        int col = c * 128 + fcol;
        bfrag[c] = *reinterpret_cast<const bf16x8*>(WrT + (size_t)col * 32 + quad * 8);
        brv[c] = br[col];
    }

    __shared__ __align__(16) float srow[2][16][20];  // [j,fs,-,-|u1 -,|u2 -,|u3 -,pad]

    int tile = blockIdx.x;
    bf16x8 af;
    if (tile < nt) {
        if (t < 256)
            srow[0][t >> 4][t & 15] = recf[((size_t)tile * 16 + (t >> 4)) * 32 + 16 + (t & 15)];
        af = *reinterpret_cast<const bf16x8*>(rec + ((size_t)tile * 16 + l16) * 128 + quad * 16);
    }

    for (int k = 0; tile < nt; ++k, tile += MSG_GRID) {
        int p = k & 1;
        int info = __builtin_amdgcn_readfirstlane(tile_node[tile]);  // SGPR
        int nr = ((info >> 16) + 3) >> 2;                            // ceil(rows/4)
        __syncthreads();   // publishes srow[p]; reads of srow[p^1] all done

        f32x4 acc[8];
        #pragma unroll
        for (int c = 0; c < 8; ++c) {
            f32x4 z = {0.f, 0.f, 0.f, 0.f};
            acc[c] = __builtin_amdgcn_mfma_f32_16x16x32_bf16(af, bfrag[c], z, 0, 0, 0);
        }

        // stage NEXT tile (header -> srow[p^1], A-frag -> af) under the epilogue
        int tn = tile + MSG_GRID;
        if (tn < nt) {
            if (t < 256)
                srow[p ^ 1][t >> 4][t & 15] = recf[((size_t)tn * 16 + (t >> 4)) * 32 + 16 + (t & 15)];
            af = *reinterpret_cast<const bf16x8*>(rec + ((size_t)tn * 16 + l16) * 128 + quad * 16);
        }

        float ds = 0.f, d0 = 0.f, d1 = 0.f, d2 = 0.f;
        #pragma unroll
        for (int r = 0; r < 4; ++r) {
            if (r >= nr) break;                  // block-uniform (SGPR) skip
            const float* rw = srow[p][quad * 4 + r];
            float2 jf = *reinterpret_cast<const float2*>(rw);
            f32x4 U1 = *reinterpret_cast<const f32x4*>(rw + 4);
            f32x4 U2 = *reinterpret_cast<const f32x4*>(rw + 8);
            f32x4 U3 = *reinterpret_cast<const f32x4*>(rw + 12);
            int j = __float_as_int(jf.x);
            float fs = jf.y;
            size_t o = (size_t)j * 128 + fcol;
            u16x8 ph = *reinterpret_cast<const u16x8*>(phi2 + o * 8);
            ushort4 vb = *reinterpret_cast<const ushort4*>(vbf2 + o * 4);
            float x[8];
            #pragma unroll
            for (int c = 0; c < 8; ++c)
                x[c] = bf2f(ph[c]) * (acc[c][r] + brv[c] * fs);
            float vjx = bf2f(vb.x), vjy = bf2f(vb.y), vjz = bf2f(vb.z);

            ds += x[0];
            d0 += vjx * x[1] + U1.x * x[2] + U2.x * x[3] + U3.x * x[4]
                + x[5] * (vjy * U1.z - vjz * U1.y)
                + x[6] * (vjy * U2.z - vjz * U2.y)
                + x[7] * (vjy * U3.z - vjz * U3.y);
            d1 += vjy * x[1] + U1.y * x[2] + U2.y * x[3] + U3.y * x[4]
                + x[5] * (vjz * U1.x - vjx * U1.z)
                + x[6] * (vjz * U2.x - vjx * U2.z)
                + x[7] * (vjz * U3.x - vjx * U3.z);
            d2 += vjz * x[1] + U1.z * x[2] + U2.z * x[3] + U3.z * x[4]
                + x[5] * (vjx * U1.y - vjy * U1.x)
                + x[6] * (vjx * U2.y - vjy * U2.x)
                + x[7] * (vjx * U3.y - vjy * U3.x);
        }

        ds += __shfl_xor(ds, 16); ds += __shfl_xor(ds, 32);
        d0 += __shfl_xor(d0, 16); d0 += __shfl_xor(d0, 32);
        d1 += __shfl_xor(d1, 16); d1 += __shfl_xor(d1, 32);
        d2 += __shfl_xor(d2, 16); d2 += __shfl_xor(d2, 32);

        if (quad == 0) {
            int node = info & 0xffff;
            atomicAdd(&out0[(size_t)node * 128 + fcol], ds);
            size_t vo = (size_t)node * 384 + fcol;
            atomicAdd(&out1[vo], d0);
            atomicAdd(&out1[vo + 128], d1);
            atomicAdd(&out1[vo + 256], d2);
        }
    }
}

// ---------------------------------------------------------------------------
extern "C" void kernel_launch(void* const* d_in, const int* in_sizes, int n_in,
                              void* d_out, int out_size, void* d_ws, size_t ws_size,
                              hipStream_t stream) {
    const float* s  = (const float*)d_in[0];
    const float* v  = (const float*)d_in[1];
    const float* R1 = (const float*)d_in[2];
    const float* R2 = (const float*)d_in[3];
    const float* R3 = (const float*)d_in[4];
    const float* f1 = (const float*)d_in[5];
    const float* f2 = (const float*)d_in[6];
    const float* f3 = (const float*)d_in[7];
    const float* u1 = (const float*)d_in[8];
    const float* u2 = (const float*)d_in[9];
    const float* u3 = (const float*)d_in[10];
    const int*  eix = (const int*)d_in[11];
    const float* W1 = (const float*)d_in[12];
    const float* b1 = (const float*)d_in[13];
    const float* W2 = (const float*)d_in[14];
    const float* b2 = (const float*)d_in[15];
    const float* Wr = (const float*)d_in[16];
    const float* br = (const float*)d_in[17];

    char* ws = (char*)d_ws;
    size_t off = 0;
    auto alloc = [&](size_t bytes) -> void* {
        void* p = ws + off;
        off = (off + bytes + 255) & ~(size_t)255;
        return p;
    };
    int* cnt       = (int*)alloc((size_t)N_NODES * 4);
    int* cursor    = (int*)alloc((size_t)N_NODES * 4);
    int* nb        = (int*)alloc((size_t)N_NODES * 4);
    int* tile_node = (int*)alloc((size_t)MAXT * 4);
    int* ntiles    = (int*)alloc(4);
    char* rec            = (char*)alloc((size_t)NSLOT * 128);
    unsigned short* vbf2 = (unsigned short*)alloc((size_t)N_NODES * 128 * 4 * 2);
    unsigned short* phi2 = (unsigned short*)alloc((size_t)N_NODES * 1024 * 2);
    unsigned short* W1T  = (unsigned short*)alloc(128 * 128 * 2);
    unsigned short* W2T  = (unsigned short*)alloc(1024 * 128 * 2);
    unsigned short* WrT  = (unsigned short*)alloc(1024 * 32 * 2);
    (void)ws_size; (void)in_sizes; (void)n_in; (void)out_size;

    float* out0 = (float*)d_out;
    float* out1 = out0 + (size_t)N_NODES * 128;

    hipMemsetAsync(cnt, 0, (size_t)N_NODES * 4, stream);
    init_kernel<<<5000, 256, 0, stream>>>(s, v, eix, W1, W2, Wr,
                                          out0, out1, vbf2, cnt, W1T, W2T, WrT);
    scan_phi_kernel<<<PHI_BLOCKS + 1, 256, 0, stream>>>(
        cnt, cursor, nb, tile_node, ntiles, s, W1T, b1, W2T, b2, phi2);
    rc_pad_kernel<<<RC_BLOCKS + PAD_BLOCKS, 256, 0, stream>>>(
        R1, R2, R3, f1, f2, f3, u1, u2, u3, eix, cnt, nb, cursor, rec);
    msg_kernel<<<MSG_GRID, 512, 0, stream>>>(rec, phi2, vbf2, WrT, br,
                                             tile_node, ntiles, out0, out1);
}

// Round 11
// 343.788 us; speedup vs baseline: 1.2842x; 1.1249x over previous
//
#include <hip/hip_runtime.h>

#define N_NODES 10000
#define N_EDGES 160000
#define MAXHALF  28750              // >= sum(ceil(deg/8)) <= (E + 7N)/8
#define NSLOT8   230016             // (MAXHALF+1)*8 slots, +dummy half
#define MAXT     14400              // >= (MAXHALF+1)/2 paired tiles
#define MSG_GRID 5000               // strided; nt ~ 12200 -> <=3 iters/block
#define PHI_BLOCKS 628
#define RC_BLOCKS 5000              // E*8 / 256
#define PAD_BLOCKS 313              // (N*8 + 8) / 256 rounded up

typedef __attribute__((ext_vector_type(8))) __bf16 bf16x8;
typedef __attribute__((ext_vector_type(8))) unsigned short u16x8;
typedef __attribute__((ext_vector_type(4))) float f32x4;

static __device__ __forceinline__ unsigned short f2bf(float x) {
    union { float f; unsigned u; } un;
    un.f = x;
    unsigned r = un.u + 0x7fffu + ((un.u >> 16) & 1u);  // RNE
    return (unsigned short)(r >> 16);
}

static __device__ __forceinline__ float bf2f(unsigned short h) {
    union { unsigned u; float f; } un;
    un.u = ((unsigned)h) << 16;
    return un.f;
}

// ---------------------------------------------------------------------------
// Fused init: float4 copies, weight transpose->bf16, vbf2 packing, degree
// histogram. Grid = 5000x256.
// ---------------------------------------------------------------------------
__global__ __launch_bounds__(256) void init_kernel(
    const float* __restrict__ s, const float* __restrict__ v,
    const int* __restrict__ eix,
    const float* __restrict__ W1, const float* __restrict__ W2,
    const float* __restrict__ Wr,
    float* __restrict__ out0, float* __restrict__ out1,
    unsigned short* __restrict__ vbf2, int* __restrict__ cnt,
    unsigned short* __restrict__ W1T, unsigned short* __restrict__ W2T,
    unsigned short* __restrict__ WrT)
{
    int tid = blockIdx.x * 256 + threadIdx.x;
    if (tid < N_NODES * 96)                      // out1 = v, float4
        reinterpret_cast<float4*>(out1)[tid] = reinterpret_cast<const float4*>(v)[tid];
    if (tid < N_NODES * 32)                      // out0 = s, float4
        reinterpret_cast<float4*>(out0)[tid] = reinterpret_cast<const float4*>(s)[tid];
    if (tid < N_NODES * 128) {                   // vbf2[n][f] = {vx,vy,vz,0} bf16
        int n = tid >> 7, f = tid & 127;
        ushort4 q;
        q.x = f2bf(v[(size_t)n * 384 + f]);
        q.y = f2bf(v[(size_t)n * 384 + 128 + f]);
        q.z = f2bf(v[(size_t)n * 384 + 256 + f]);
        q.w = 0;
        *reinterpret_cast<ushort4*>(vbf2 + (size_t)tid * 4) = q;
    }
    if (tid < 131072) {                          // W2T [1024][128]
        int n = tid >> 7, k = tid & 127;
        W2T[tid] = f2bf(W2[k * 1024 + n]);
    }
    if (tid < 16384) {                           // W1T [128][128]
        int n = tid >> 7, k = tid & 127;
        W1T[tid] = f2bf(W1[k * 128 + n]);
    }
    if (tid < 32768) {                           // WrT [1024][32]
        int n = tid >> 5, k = tid & 31;
        WrT[tid] = f2bf(Wr[k * 1024 + n]);
    }
    if (tid < N_EDGES) atomicAdd(&cnt[eix[tid]], 1);
}

// ---------------------------------------------------------------------------
// Fused scan + phi. Blocks [0, PHI_BLOCKS) = phi; block PHI_BLOCKS = one-block
// HALF-TILE scan (8-edge quantum) hidden under phi:
//   nb/cursor = 8*prefix(ceil(deg/8));  half_node[h] = owner of half-tile h;
//   tile t pairs halves 2t,2t+1 -> tile_node[t] = nodeA | nodeB<<16.
// ---------------------------------------------------------------------------
__global__ __launch_bounds__(256) void scan_phi_kernel(
    const int* __restrict__ cnt, int* __restrict__ cursor,
    int* __restrict__ nb, int* __restrict__ half_node,
    int* __restrict__ tile_node, int* __restrict__ ntiles,
    const float* __restrict__ s, const unsigned short* __restrict__ W1T,
    const float* __restrict__ b1, const unsigned short* __restrict__ W2T,
    const float* __restrict__ b2, unsigned short* __restrict__ phi2)
{
    __shared__ unsigned short h_lds[64][136];
    __shared__ int ws4[4];
    int bx = blockIdx.x;
    int t = threadIdx.x, lane = t & 63, w = t >> 6;

    if (bx == PHI_BLOCKS) {
        // ---------------- scan: 256 threads x 40 nodes, half-tile units ----
        int n0 = t * 40;
        int sum = 0;
        for (int i = 0; i < 40; ++i) {
            int n = n0 + i;
            if (n < N_NODES) sum += (cnt[n] + 7) >> 3;
        }
        int x = sum;
        #pragma unroll
        for (int o = 1; o < 64; o <<= 1) {
            int y = __shfl_up(x, o);
            if (lane >= o) x += y;
        }
        if (lane == 63) ws4[w] = x;
        __syncthreads();
        if (t < 4) {
            int vsum = ws4[t];
            #pragma unroll
            for (int o = 1; o < 4; o <<= 1) {
                int y = __shfl_up(vsum, o);
                if (lane >= o) vsum += y;
            }
            ws4[t] = vsum;               // inclusive wave sums
        }
        __syncthreads();
        int wb = w ? ws4[w - 1] : 0;
        int run = wb + x - sum;          // exclusive prefix, half-tile units
        for (int i = 0; i < 40; ++i) {
            int n = n0 + i;
            if (n >= N_NODES) break;
            int deg = cnt[n];
            int c8 = (deg + 7) >> 3;
            nb[n] = run * 8;
            cursor[n] = run * 8;
            for (int k = 0; k < c8; ++k) half_node[run + k] = n;
            run += c8;
        }
        int total = ws4[3];
        if (t == 0) {
            half_node[total] = 0;        // dummy half for odd pairing
            ntiles[0] = (total + 1) >> 1;
            ntiles[1] = total;
        }
        __syncthreads();                 // half_node writes visible in-block
        int nt0 = (total + 1) >> 1;
        for (int t4 = t; t4 < nt0; t4 += 256)
            tile_node[t4] = half_node[2 * t4] | (half_node[2 * t4 + 1] << 16);
        return;
    }

    // ---------------- phi: silu(s@W1+b1)@W2+b2 ----------------
    int quad = lane >> 4, l16 = lane & 15;
    int m0 = (bx >> 2) * 64;
    int colg = bx & 3;

    int arow = m0 + w * 16 + l16;
    if (arow > N_NODES - 1) arow = N_NODES - 1;
    bf16x8 afr[4];
    #pragma unroll
    for (int ks = 0; ks < 4; ++ks) {
        const float* sp = s + (size_t)arow * 128 + ks * 32 + quad * 8;
        #pragma unroll
        for (int jj = 0; jj < 8; ++jj) afr[ks][jj] = (__bf16)sp[jj];
    }
    #pragma unroll
    for (int cg = 0; cg < 8; ++cg) {
        int col = cg * 16 + l16;
        f32x4 acc = {0.f, 0.f, 0.f, 0.f};
        #pragma unroll
        for (int ks = 0; ks < 4; ++ks) {
            bf16x8 bf = *reinterpret_cast<const bf16x8*>(W1T + (size_t)col * 128 + ks * 32 + quad * 8);
            acc = __builtin_amdgcn_mfma_f32_16x16x32_bf16(afr[ks], bf, acc, 0, 0, 0);
        }
        float bb = b1[col];
        #pragma unroll
        for (int r = 0; r < 4; ++r) {
            int row = w * 16 + quad * 4 + r;
            float val = acc[r] + bb;
            h_lds[row][col] = f2bf(val / (1.f + __expf(-val)));
        }
    }
    __syncthreads();

    bf16x8 a2[4][4];
    #pragma unroll
    for (int rg = 0; rg < 4; ++rg)
        #pragma unroll
        for (int ks = 0; ks < 4; ++ks)
            a2[rg][ks] = *reinterpret_cast<const bf16x8*>(&h_lds[rg * 16 + l16][ks * 32 + quad * 8]);
    #pragma unroll
    for (int i = 0; i < 4; ++i) {
        int col = colg * 256 + w * 64 + i * 16 + l16;
        f32x4 acc2[4] = {{0,0,0,0},{0,0,0,0},{0,0,0,0},{0,0,0,0}};
        #pragma unroll
        for (int ks = 0; ks < 4; ++ks) {
            bf16x8 bf = *reinterpret_cast<const bf16x8*>(W2T + (size_t)col * 128 + ks * 32 + quad * 8);
            #pragma unroll
            for (int rg = 0; rg < 4; ++rg)
                acc2[rg] = __builtin_amdgcn_mfma_f32_16x16x32_bf16(a2[rg][ks], bf, acc2[rg], 0, 0, 0);
        }
        float bb = b2[col];
        int f = col & 127, cc = col >> 7;
        #pragma unroll
        for (int rg = 0; rg < 4; ++rg)
            #pragma unroll
            for (int r = 0; r < 4; ++r) {
                int row = m0 + rg * 16 + quad * 4 + r;
                if (row < N_NODES)
                    phi2[(size_t)row * 1024 + f * 8 + cc] = f2bf(acc2[rg][r] + bb);
            }
    }
}

// ---------------------------------------------------------------------------
// rc + pad on the 128-B interleaved record at 8-aligned CSR slots.
//  blocks [0, RC_BLOCKS):      per-edge Rc/hdr at CSR slot
//  blocks [RC_BLOCKS, +PAD):   zero <=7 pad slots/node + dummy half if odd
// ---------------------------------------------------------------------------
__global__ __launch_bounds__(256) void rc_pad_kernel(
    const float* __restrict__ R1, const float* __restrict__ R2,
    const float* __restrict__ R3,
    const float* __restrict__ f1, const float* __restrict__ f2,
    const float* __restrict__ f3,
    const float* __restrict__ u1, const float* __restrict__ u2,
    const float* __restrict__ u3,
    const int* __restrict__ eix, const int* __restrict__ cnt,
    const int* __restrict__ nb, int* __restrict__ cursor,
    const int* __restrict__ ntiles, char* __restrict__ rec)
{
    int bx = blockIdx.x;
    if (bx >= RC_BLOCKS) {
        int t2 = (bx - RC_BLOCKS) * 256 + threadIdx.x;
        if (t2 < N_NODES * 8) {
            int n = t2 >> 3, r = t2 & 7;
            int deg = cnt[n], c8 = (deg + 7) >> 3;
            int p = deg + r;
            if (p < c8 * 8) {
                size_t slot = (size_t)nb[n] + p;
                f32x4 z = {0.f, 0.f, 0.f, 0.f};
                f32x4* rp = reinterpret_cast<f32x4*>(rec + slot * 128);
                #pragma unroll
                for (int q = 0; q < 8; ++q) rp[q] = z;
            }
        } else if (t2 < N_NODES * 8 + 8) {
            int nhalf = ntiles[1];
            if (nhalf & 1) {                     // zero the dummy half-tile
                size_t slot = (size_t)nhalf * 8 + (t2 - N_NODES * 8);
                f32x4 z = {0.f, 0.f, 0.f, 0.f};
                f32x4* rp = reinterpret_cast<f32x4*>(rec + slot * 128);
                #pragma unroll
                for (int q = 0; q < 8; ++q) rp[q] = z;
            }
        }
        return;
    }

    // ---------------- rc: Rc + packed header at CSR slot ----------------
    int tid = bx * 256 + threadIdx.x;            // exactly E*8 threads
    int e = tid >> 3, sub = tid & 7;
    int lane = threadIdx.x & 63;
    float a = f1[e], b = f2[e], c = f3[e];
    int k0 = sub * 4;
    float4 r1 = *reinterpret_cast<const float4*>(R1 + (size_t)e * 32 + k0);
    float4 r2 = *reinterpret_cast<const float4*>(R2 + (size_t)e * 32 + k0);
    float4 r3 = *reinterpret_cast<const float4*>(R3 + (size_t)e * 32 + k0);
    ushort4 o;
    o.x = f2bf(r1.x * a + r2.x * b + r3.x * c);
    o.y = f2bf(r1.y * a + r2.y * b + r3.y * c);
    o.z = f2bf(r1.z * a + r2.z * b + r3.z * c);
    o.w = f2bf(r1.w * a + r2.w * b + r3.w * c);
    int slot = 0;
    if (sub == 0) slot = atomicAdd(&cursor[eix[e]], 1);
    slot = __shfl(slot, lane & 56);              // broadcast from sub0
    *reinterpret_cast<ushort4*>(rec + (size_t)slot * 128 + k0 * 2) = o;
    float* hf = reinterpret_cast<float*>(rec + (size_t)slot * 128 + 64);
    if (sub == 0) {
        float4 h;
        h.x = __int_as_float(eix[N_EDGES + e]);  // j
        h.y = a + b + c;                         // fsum
        h.z = 0.f; h.w = 0.f;
        *reinterpret_cast<float4*>(hf) = h;
    } else if (sub < 4) {
        const float* up = (sub == 1 ? u1 : (sub == 2 ? u2 : u3)) + (size_t)e * 3;
        float4 h;
        h.x = up[0]; h.y = up[1]; h.z = up[2]; h.w = 0.f;
        *reinterpret_cast<float4*>(hf + sub * 4) = h;
    }
}

// ---------------------------------------------------------------------------
// Main msg kernel: r6 double-buffer pipeline on PAIRED half-tiles. Rows 0-7 =
// half A (nodeA), rows 8-15 = half B (nodeB). Per-tile body is identical to
// r6 (no branches, no skip logic -> VGPR 64). Reduction stops at xor16 (A in
// quads 0/1, B in quads 2/3); quads 0 and 2 flush their half's node.
// ---------------------------------------------------------------------------
__global__ __launch_bounds__(512) void msg_kernel(
    const char* __restrict__ rec,
    const unsigned short* __restrict__ phi2, const unsigned short* __restrict__ vbf2,
    const unsigned short* __restrict__ WrT, const float* __restrict__ br,
    const int* __restrict__ tile_node, const int* __restrict__ ntiles,
    float* __restrict__ out0, float* __restrict__ out1)
{
    int t = threadIdx.x, lane = t & 63, w = t >> 6;
    int quad = lane >> 4, l16 = lane & 15;
    int fcol = w * 16 + l16;
    const int nt = *ntiles;
    const float* recf = reinterpret_cast<const float*>(rec);

    bf16x8 bfrag[8];
    float brv[8];
    #pragma unroll
    for (int c = 0; c < 8; ++c) {
        int col = c * 128 + fcol;
        bfrag[c] = *reinterpret_cast<const bf16x8*>(WrT + (size_t)col * 32 + quad * 8);
        brv[c] = br[col];
    }

    __shared__ __align__(16) float srow[2][16][20];  // [j,fs,-,-|u1 -,|u2 -,|u3 -,pad]

    int tile = blockIdx.x;
    bf16x8 af;
    if (tile < nt) {
        if (t < 256)
            srow[0][t >> 4][t & 15] = recf[((size_t)tile * 16 + (t >> 4)) * 32 + 16 + (t & 15)];
        af = *reinterpret_cast<const bf16x8*>(rec + ((size_t)tile * 16 + l16) * 128 + quad * 16);
    }

    for (int k = 0; tile < nt; ++k, tile += MSG_GRID) {
        int p = k & 1;
        __syncthreads();   // publishes srow[p]; reads of srow[p^1] all done

        f32x4 acc[8];
        #pragma unroll
        for (int c = 0; c < 8; ++c) {
            f32x4 z = {0.f, 0.f, 0.f, 0.f};
            acc[c] = __builtin_amdgcn_mfma_f32_16x16x32_bf16(af, bfrag[c], z, 0, 0, 0);
        }

        // stage NEXT tile (header -> srow[p^1], A-frag -> af) under the epilogue
        int tn = tile + MSG_GRID;
        if (tn < nt) {
            if (t < 256)
                srow[p ^ 1][t >> 4][t & 15] = recf[((size_t)tn * 16 + (t >> 4)) * 32 + 16 + (t & 15)];
            af = *reinterpret_cast<const bf16x8*>(rec + ((size_t)tn * 16 + l16) * 128 + quad * 16);
        }

        float ds = 0.f, d0 = 0.f, d1 = 0.f, d2 = 0.f;
        #pragma unroll
        for (int r = 0; r < 4; ++r) {
            const float* rw = srow[p][quad * 4 + r];
            float2 jf = *reinterpret_cast<const float2*>(rw);
            f32x4 U1 = *reinterpret_cast<const f32x4*>(rw + 4);
            f32x4 U2 = *reinterpret_cast<const f32x4*>(rw + 8);
            f32x4 U3 = *reinterpret_cast<const f32x4*>(rw + 12);
            int j = __float_as_int(jf.x);
            float fs = jf.y;
            size_t o = (size_t)j * 128 + fcol;
            u16x8 ph = *reinterpret_cast<const u16x8*>(phi2 + o * 8);
            ushort4 vb = *reinterpret_cast<const ushort4*>(vbf2 + o * 4);
            float x[8];
            #pragma unroll
            for (int c = 0; c < 8; ++c)
                x[c] = bf2f(ph[c]) * (acc[c][r] + brv[c] * fs);
            float vjx = bf2f(vb.x), vjy = bf2f(vb.y), vjz = bf2f(vb.z);

            ds += x[0];
            d0 += vjx * x[1] + U1.x * x[2] + U2.x * x[3] + U3.x * x[4]
                + x[5] * (vjy * U1.z - vjz * U1.y)
                + x[6] * (vjy * U2.z - vjz * U2.y)
                + x[7] * (vjy * U3.z - vjz * U3.y);
            d1 += vjy * x[1] + U1.y * x[2] + U2.y * x[3] + U3.y * x[4]
                + x[5] * (vjz * U1.x - vjx * U1.z)
                + x[6] * (vjz * U2.x - vjx * U2.z)
                + x[7] * (vjz * U3.x - vjx * U3.z);
            d2 += vjz * x[1] + U1.z * x[2] + U2.z * x[3] + U3.z * x[4]
                + x[5] * (vjx * U1.y - vjy * U1.x)
                + x[6] * (vjx * U2.y - vjy * U2.x)
                + x[7] * (vjx * U3.y - vjy * U3.x);
        }

        // xor16 only: quads {0,1} hold rows 0-7 (half A), {2,3} rows 8-15 (half B)
        ds += __shfl_xor(ds, 16);
        d0 += __shfl_xor(d0, 16);
        d1 += __shfl_xor(d1, 16);
        d2 += __shfl_xor(d2, 16);

        if (!(quad & 1)) {
            int ab = tile_node[tile];
            int node = quad ? (ab >> 16) : (ab & 0xffff);
            atomicAdd(&out0[(size_t)node * 128 + fcol], ds);
            size_t vo = (size_t)node * 384 + fcol;
            atomicAdd(&out1[vo], d0);
            atomicAdd(&out1[vo + 128], d1);
            atomicAdd(&out1[vo + 256], d2);
        }
    }
}

// ---------------------------------------------------------------------------
extern "C" void kernel_launch(void* const* d_in, const int* in_sizes, int n_in,
                              void* d_out, int out_size, void* d_ws, size_t ws_size,
                              hipStream_t stream) {
    const float* s  = (const float*)d_in[0];
    const float* v  = (const float*)d_in[1];
    const float* R1 = (const float*)d_in[2];
    const float* R2 = (const float*)d_in[3];
    const float* R3 = (const float*)d_in[4];
    const float* f1 = (const float*)d_in[5];
    const float* f2 = (const float*)d_in[6];
    const float* f3 = (const float*)d_in[7];
    const float* u1 = (const float*)d_in[8];
    const float* u2 = (const float*)d_in[9];
    const float* u3 = (const float*)d_in[10];
    const int*  eix = (const int*)d_in[11];
    const float* W1 = (const float*)d_in[12];
    const float* b1 = (const float*)d_in[13];
    const float* W2 = (const float*)d_in[14];
    const float* b2 = (const float*)d_in[15];
    const float* Wr = (const float*)d_in[16];
    const float* br = (const float*)d_in[17];

    char* ws = (char*)d_ws;
    size_t off = 0;
    auto alloc = [&](size_t bytes) -> void* {
        void* p = ws + off;
        off = (off + bytes + 255) & ~(size_t)255;
        return p;
    };
    int* cnt       = (int*)alloc((size_t)N_NODES * 4);
    int* cursor    = (int*)alloc((size_t)N_NODES * 4);
    int* nb        = (int*)alloc((size_t)N_NODES * 4);
    int* half_node = (int*)alloc((size_t)(MAXHALF + 2) * 4);
    int* tile_node = (int*)alloc((size_t)MAXT * 4);
    int* ntiles    = (int*)alloc(8);
    char* rec            = (char*)alloc((size_t)NSLOT8 * 128);
    unsigned short* vbf2 = (unsigned short*)alloc((size_t)N_NODES * 128 * 4 * 2);
    unsigned short* phi2 = (unsigned short*)alloc((size_t)N_NODES * 1024 * 2);
    unsigned short* W1T  = (unsigned short*)alloc(128 * 128 * 2);
    unsigned short* W2T  = (unsigned short*)alloc(1024 * 128 * 2);
    unsigned short* WrT  = (unsigned short*)alloc(1024 * 32 * 2);
    (void)ws_size; (void)in_sizes; (void)n_in; (void)out_size;

    float* out0 = (float*)d_out;
    float* out1 = out0 + (size_t)N_NODES * 128;

    hipMemsetAsync(cnt, 0, (size_t)N_NODES * 4, stream);
    init_kernel<<<5000, 256, 0, stream>>>(s, v, eix, W1, W2, Wr,
                                          out0, out1, vbf2, cnt, W1T, W2T, WrT);
    scan_phi_kernel<<<PHI_BLOCKS + 1, 256, 0, stream>>>(
        cnt, cursor, nb, half_node, tile_node, ntiles,
        s, W1T, b1, W2T, b2, phi2);
    rc_pad_kernel<<<RC_BLOCKS + PAD_BLOCKS, 256, 0, stream>>>(
        R1, R2, R3, f1, f2, f3, u1, u2, u3, eix, cnt, nb, cursor, ntiles, rec);
    msg_kernel<<<MSG_GRID, 512, 0, stream>>>(rec, phi2, vbf2, WrT, br,
                                             tile_node, ntiles, out0, out1);
}

// Round 12
// 324.599 us; speedup vs baseline: 1.3601x; 1.0591x over previous
//
#include <hip/hip_runtime.h>

#define N_NODES 10000
#define N_EDGES 160000
#define MAXT     19400              // >= sum(ceil(deg/16)) <= (E + 15N)/16 = 19375
#define NSLOT    (MAXT * 16 + 16)   // 16-aligned CSR slots + guard
#define MSG_GRID 5000               // x4 strided tiles = 20000 slots
#define PHI_BLOCKS 628
#define RC_BLOCKS 5000              // E*8 / 256
#define PAD_BLOCKS 625              // N*16 / 256

typedef __attribute__((ext_vector_type(8))) __bf16 bf16x8;
typedef __attribute__((ext_vector_type(8))) unsigned short u16x8;
typedef __attribute__((ext_vector_type(4))) float f32x4;

static __device__ __forceinline__ unsigned short f2bf(float x) {
    union { float f; unsigned u; } un;
    un.f = x;
    unsigned r = un.u + 0x7fffu + ((un.u >> 16) & 1u);  // RNE
    return (unsigned short)(r >> 16);
}

static __device__ __forceinline__ float bf2f(unsigned short h) {
    union { unsigned u; float f; } un;
    un.u = ((unsigned)h) << 16;
    return un.f;
}

// ---------------------------------------------------------------------------
// Fused init: float4 copies, weight transpose->bf16, vbf2 packing, degree
// histogram. Grid = 5000x256.
// ---------------------------------------------------------------------------
__global__ __launch_bounds__(256) void init_kernel(
    const float* __restrict__ s, const float* __restrict__ v,
    const int* __restrict__ eix,
    const float* __restrict__ W1, const float* __restrict__ W2,
    const float* __restrict__ Wr,
    float* __restrict__ out0, float* __restrict__ out1,
    unsigned short* __restrict__ vbf2, int* __restrict__ cnt,
    unsigned short* __restrict__ W1T, unsigned short* __restrict__ W2T,
    unsigned short* __restrict__ WrT)
{
    int tid = blockIdx.x * 256 + threadIdx.x;
    if (tid < N_NODES * 96)                      // out1 = v, float4
        reinterpret_cast<float4*>(out1)[tid] = reinterpret_cast<const float4*>(v)[tid];
    if (tid < N_NODES * 32)                      // out0 = s, float4
        reinterpret_cast<float4*>(out0)[tid] = reinterpret_cast<const float4*>(s)[tid];
    if (tid < N_NODES * 128) {                   // vbf2[n][f] = {vx,vy,vz,0} bf16
        int n = tid >> 7, f = tid & 127;
        ushort4 q;
        q.x = f2bf(v[(size_t)n * 384 + f]);
        q.y = f2bf(v[(size_t)n * 384 + 128 + f]);
        q.z = f2bf(v[(size_t)n * 384 + 256 + f]);
        q.w = 0;
        *reinterpret_cast<ushort4*>(vbf2 + (size_t)tid * 4) = q;
    }
    if (tid < 131072) {                          // W2T [1024][128]
        int n = tid >> 7, k = tid & 127;
        W2T[tid] = f2bf(W2[k * 1024 + n]);
    }
    if (tid < 16384) {                           // W1T [128][128]
        int n = tid >> 7, k = tid & 127;
        W1T[tid] = f2bf(W1[k * 128 + n]);
    }
    if (tid < 32768) {                           // WrT [1024][32]
        int n = tid >> 5, k = tid & 31;
        WrT[tid] = f2bf(Wr[k * 1024 + n]);
    }
    if (tid < N_EDGES) atomicAdd(&cnt[eix[tid]], 1);
}

// ---------------------------------------------------------------------------
// Fused scan + phi. Blocks [0, PHI_BLOCKS) = phi (independent of scan);
// block PHI_BLOCKS = single-block scan (40 nodes/thread, one shfl pass) that
// hides entirely under phi.
// ---------------------------------------------------------------------------
__global__ __launch_bounds__(256) void scan_phi_kernel(
    const int* __restrict__ cnt, int* __restrict__ cursor,
    int* __restrict__ nb, int* __restrict__ tile_node,
    int* __restrict__ ntiles,
    const float* __restrict__ s, const unsigned short* __restrict__ W1T,
    const float* __restrict__ b1, const unsigned short* __restrict__ W2T,
    const float* __restrict__ b2, unsigned short* __restrict__ phi2)
{
    __shared__ unsigned short h_lds[64][136];
    __shared__ int ws4[4];
    int bx = blockIdx.x;
    int t = threadIdx.x, lane = t & 63, w = t >> 6;

    if (bx == PHI_BLOCKS) {
        // ---------------- scan: 256 threads x 40 nodes ----------------
        int n0 = t * 40;
        int sum = 0;
        for (int i = 0; i < 40; ++i) {
            int n = n0 + i;
            if (n < N_NODES) sum += (cnt[n] + 15) >> 4;
        }
        int x = sum;
        #pragma unroll
        for (int o = 1; o < 64; o <<= 1) {
            int y = __shfl_up(x, o);
            if (lane >= o) x += y;
        }
        if (lane == 63) ws4[w] = x;
        __syncthreads();
        if (t < 4) {
            int vsum = ws4[t];
            #pragma unroll
            for (int o = 1; o < 4; o <<= 1) {
                int y = __shfl_up(vsum, o);
                if (lane >= o) vsum += y;
            }
            ws4[t] = vsum;               // inclusive wave sums
        }
        __syncthreads();
        int wb = w ? ws4[w - 1] : 0;
        int run = wb + x - sum;          // exclusive prefix, tile units
        for (int i = 0; i < 40; ++i) {
            int n = n0 + i;
            if (n >= N_NODES) break;
            int tc = (cnt[n] + 15) >> 4;
            nb[n] = run * 16;
            cursor[n] = run * 16;
            for (int k = 0; k < tc; ++k) tile_node[run + k] = n;
            run += tc;
        }
        if (t == 255) *ntiles = run;
        return;
    }

    // ---------------- phi: silu(s@W1+b1)@W2+b2 ----------------
    int quad = lane >> 4, l16 = lane & 15;
    int m0 = (bx >> 2) * 64;
    int colg = bx & 3;

    int arow = m0 + w * 16 + l16;
    if (arow > N_NODES - 1) arow = N_NODES - 1;
    bf16x8 afr[4];
    #pragma unroll
    for (int ks = 0; ks < 4; ++ks) {
        const float* sp = s + (size_t)arow * 128 + ks * 32 + quad * 8;
        #pragma unroll
        for (int jj = 0; jj < 8; ++jj) afr[ks][jj] = (__bf16)sp[jj];
    }
    #pragma unroll
    for (int cg = 0; cg < 8; ++cg) {
        int col = cg * 16 + l16;
        f32x4 acc = {0.f, 0.f, 0.f, 0.f};
        #pragma unroll
        for (int ks = 0; ks < 4; ++ks) {
            bf16x8 bf = *reinterpret_cast<const bf16x8*>(W1T + (size_t)col * 128 + ks * 32 + quad * 8);
            acc = __builtin_amdgcn_mfma_f32_16x16x32_bf16(afr[ks], bf, acc, 0, 0, 0);
        }
        float bb = b1[col];
        #pragma unroll
        for (int r = 0; r < 4; ++r) {
            int row = w * 16 + quad * 4 + r;
            float val = acc[r] + bb;
            h_lds[row][col] = f2bf(val / (1.f + __expf(-val)));
        }
    }
    __syncthreads();

    bf16x8 a2[4][4];
    #pragma unroll
    for (int rg = 0; rg < 4; ++rg)
        #pragma unroll
        for (int ks = 0; ks < 4; ++ks)
            a2[rg][ks] = *reinterpret_cast<const bf16x8*>(&h_lds[rg * 16 + l16][ks * 32 + quad * 8]);
    #pragma unroll
    for (int i = 0; i < 4; ++i) {
        int col = colg * 256 + w * 64 + i * 16 + l16;
        f32x4 acc2[4] = {{0,0,0,0},{0,0,0,0},{0,0,0,0},{0,0,0,0}};
        #pragma unroll
        for (int ks = 0; ks < 4; ++ks) {
            bf16x8 bf = *reinterpret_cast<const bf16x8*>(W2T + (size_t)col * 128 + ks * 32 + quad * 8);
            #pragma unroll
            for (int rg = 0; rg < 4; ++rg)
                acc2[rg] = __builtin_amdgcn_mfma_f32_16x16x32_bf16(a2[rg][ks], bf, acc2[rg], 0, 0, 0);
        }
        float bb = b2[col];
        int f = col & 127, cc = col >> 7;
        #pragma unroll
        for (int rg = 0; rg < 4; ++rg)
            #pragma unroll
            for (int r = 0; r < 4; ++r) {
                int row = m0 + rg * 16 + quad * 4 + r;
                if (row < N_NODES)
                    phi2[(size_t)row * 1024 + f * 8 + cc] = f2bf(acc2[rg][r] + bb);
            }
    }
}

// ---------------------------------------------------------------------------
// rc + pad on the 128-B interleaved record: rec[slot] = {Rc 32xushort | hdr
// 16xfloat}. Per edge ONE contiguous 128B line.
//  blocks [0, RC_BLOCKS):      per-edge Rc/hdr at CSR slot
//  blocks [RC_BLOCKS, +PAD):   zero pad slots
// ---------------------------------------------------------------------------
__global__ __launch_bounds__(256) void rc_pad_kernel(
    const float* __restrict__ R1, const float* __restrict__ R2,
    const float* __restrict__ R3,
    const float* __restrict__ f1, const float* __restrict__ f2,
    const float* __restrict__ f3,
    const float* __restrict__ u1, const float* __restrict__ u2,
    const float* __restrict__ u3,
    const int* __restrict__ eix, const int* __restrict__ cnt,
    const int* __restrict__ nb, int* __restrict__ cursor,
    char* __restrict__ rec)
{
    int bx = blockIdx.x;
    if (bx >= RC_BLOCKS) {
        // ---------------- pad: zero unused slots (full 128B record) -------
        int t2 = (bx - RC_BLOCKS) * 256 + threadIdx.x;   // [0, 16N)
        int n = t2 >> 4, r = t2 & 15;
        int deg = cnt[n], tc = (deg + 15) >> 4;
        int p = deg + r;
        if (p < tc * 16) {
            size_t slot = (size_t)nb[n] + p;
            f32x4 z = {0.f, 0.f, 0.f, 0.f};
            f32x4* rp = reinterpret_cast<f32x4*>(rec + slot * 128);
            #pragma unroll
            for (int q = 0; q < 8; ++q) rp[q] = z;
        }
        return;
    }

    // ---------------- rc: Rc + packed header at CSR slot ----------------
    int tid = bx * 256 + threadIdx.x;            // exactly E*8 threads
    int e = tid >> 3, sub = tid & 7;
    int lane = threadIdx.x & 63;
    float a = f1[e], b = f2[e], c = f3[e];
    int k0 = sub * 4;
    float4 r1 = *reinterpret_cast<const float4*>(R1 + (size_t)e * 32 + k0);
    float4 r2 = *reinterpret_cast<const float4*>(R2 + (size_t)e * 32 + k0);
    float4 r3 = *reinterpret_cast<const float4*>(R3 + (size_t)e * 32 + k0);
    ushort4 o;
    o.x = f2bf(r1.x * a + r2.x * b + r3.x * c);
    o.y = f2bf(r1.y * a + r2.y * b + r3.y * c);
    o.z = f2bf(r1.z * a + r2.z * b + r3.z * c);
    o.w = f2bf(r1.w * a + r2.w * b + r3.w * c);
    int slot = 0;
    if (sub == 0) slot = atomicAdd(&cursor[eix[e]], 1);
    slot = __shfl(slot, lane & 56);              // broadcast from sub0
    *reinterpret_cast<ushort4*>(rec + (size_t)slot * 128 + k0 * 2) = o;
    float* hf = reinterpret_cast<float*>(rec + (size_t)slot * 128 + 64);
    if (sub == 0) {
        float4 h;
        h.x = __int_as_float(eix[N_EDGES + e]);  // j
        h.y = a + b + c;                         // fsum
        h.z = 0.f; h.w = 0.f;
        *reinterpret_cast<float4*>(hf) = h;
    } else if (sub < 4) {
        const float* up = (sub == 1 ? u1 : (sub == 2 ? u2 : u3)) + (size_t)e * 3;
        float4 h;
        h.x = up[0]; h.y = up[1]; h.z = up[2]; h.w = 0.f;
        *reinterpret_cast<float4*>(hf + sub * 4) = h;
    }
}

// ---------------------------------------------------------------------------
// Main msg kernel: r6 double-buffer pipeline (empirical optimum: VGPR 64,
// 4 waves/SIMD). rec is read EXACTLY ONCE -> nontemporal loads keep the 40MB
// stream from evicting the phi2/vbf2 gather working set (30MB, re-read) out
// of L2. Register-neutral change.
// ---------------------------------------------------------------------------
__global__ __launch_bounds__(512) void msg_kernel(
    const char* __restrict__ rec,
    const unsigned short* __restrict__ phi2, const unsigned short* __restrict__ vbf2,
    const unsigned short* __restrict__ WrT, const float* __restrict__ br,
    const int* __restrict__ tile_node, const int* __restrict__ ntiles,
    float* __restrict__ out0, float* __restrict__ out1)
{
    int t = threadIdx.x, lane = t & 63, w = t >> 6;
    int quad = lane >> 4, l16 = lane & 15;
    int fcol = w * 16 + l16;
    const int nt = *ntiles;
    const float* recf = reinterpret_cast<const float*>(rec);

    bf16x8 bfrag[8];
    float brv[8];
    #pragma unroll
    for (int c = 0; c < 8; ++c) {
        int col = c * 128 + fcol;
        bfrag[c] = *reinterpret_cast<const bf16x8*>(WrT + (size_t)col * 32 + quad * 8);
        brv[c] = br[col];
    }

    __shared__ __align__(16) float srow[2][16][20];  // [j,fs,-,-|u1 -,|u2 -,|u3 -,pad]

    int tile = blockIdx.x;
    bf16x8 af;
    if (tile < nt) {
        if (t < 256)
            srow[0][t >> 4][t & 15] = __builtin_nontemporal_load(
                recf + ((size_t)tile * 16 + (t >> 4)) * 32 + 16 + (t & 15));
        af = __builtin_nontemporal_load(
            reinterpret_cast<const bf16x8*>(rec + ((size_t)tile * 16 + l16) * 128 + quad * 16));
    }

    for (int k = 0; tile < nt; ++k, tile += MSG_GRID) {
        int p = k & 1;
        __syncthreads();   // publishes srow[p]; reads of srow[p^1] all done

        f32x4 acc[8];
        #pragma unroll
        for (int c = 0; c < 8; ++c) {
            f32x4 z = {0.f, 0.f, 0.f, 0.f};
            acc[c] = __builtin_amdgcn_mfma_f32_16x16x32_bf16(af, bfrag[c], z, 0, 0, 0);
        }

        // stage NEXT tile (header -> srow[p^1], A-frag -> af) under the epilogue
        int tn = tile + MSG_GRID;
        if (tn < nt) {
            if (t < 256)
                srow[p ^ 1][t >> 4][t & 15] = __builtin_nontemporal_load(
                    recf + ((size_t)tn * 16 + (t >> 4)) * 32 + 16 + (t & 15));
            af = __builtin_nontemporal_load(
                reinterpret_cast<const bf16x8*>(rec + ((size_t)tn * 16 + l16) * 128 + quad * 16));
        }

        float ds = 0.f, d0 = 0.f, d1 = 0.f, d2 = 0.f;
        #pragma unroll
        for (int r = 0; r < 4; ++r) {
            const float* rw = srow[p][quad * 4 + r];
            float2 jf = *reinterpret_cast<const float2*>(rw);
            f32x4 U1 = *reinterpret_cast<const f32x4*>(rw + 4);
            f32x4 U2 = *reinterpret_cast<const f32x4*>(rw + 8);
            f32x4 U3 = *reinterpret_cast<const f32x4*>(rw + 12);
            int j = __float_as_int(jf.x);
            float fs = jf.y;
            size_t o = (size_t)j * 128 + fcol;
            u16x8 ph = *reinterpret_cast<const u16x8*>(phi2 + o * 8);
            ushort4 vb = *reinterpret_cast<const ushort4*>(vbf2 + o * 4);
            float x[8];
            #pragma unroll
            for (int c = 0; c < 8; ++c)
                x[c] = bf2f(ph[c]) * (acc[c][r] + brv[c] * fs);
            float vjx = bf2f(vb.x), vjy = bf2f(vb.y), vjz = bf2f(vb.z);

            ds += x[0];
            d0 += vjx * x[1] + U1.x * x[2] + U2.x * x[3] + U3.x * x[4]
                + x[5] * (vjy * U1.z - vjz * U1.y)
                + x[6] * (vjy * U2.z - vjz * U2.y)
                + x[7] * (vjy * U3.z - vjz * U3.y);
            d1 += vjy * x[1] + U1.y * x[2] + U2.y * x[3] + U3.y * x[4]
                + x[5] * (vjz * U1.x - vjx * U1.z)
                + x[6] * (vjz * U2.x - vjx * U2.z)
                + x[7] * (vjz * U3.x - vjx * U3.z);
            d2 += vjz * x[1] + U1.z * x[2] + U2.z * x[3] + U3.z * x[4]
                + x[5] * (vjx * U1.y - vjy * U1.x)
                + x[6] * (vjx * U2.y - vjy * U2.x)
                + x[7] * (vjx * U3.y - vjy * U3.x);
        }

        ds += __shfl_xor(ds, 16); ds += __shfl_xor(ds, 32);
        d0 += __shfl_xor(d0, 16); d0 += __shfl_xor(d0, 32);
        d1 += __shfl_xor(d1, 16); d1 += __shfl_xor(d1, 32);
        d2 += __shfl_xor(d2, 16); d2 += __shfl_xor(d2, 32);

        if (quad == 0) {
            int node = tile_node[tile];
            atomicAdd(&out0[(size_t)node * 128 + fcol], ds);
            size_t vo = (size_t)node * 384 + fcol;
            atomicAdd(&out1[vo], d0);
            atomicAdd(&out1[vo + 128], d1);
            atomicAdd(&out1[vo + 256], d2);
        }
    }
}

// ---------------------------------------------------------------------------
extern "C" void kernel_launch(void* const* d_in, const int* in_sizes, int n_in,
                              void* d_out, int out_size, void* d_ws, size_t ws_size,
                              hipStream_t stream) {
    const float* s  = (const float*)d_in[0];
    const float* v  = (const float*)d_in[1];
    const float* R1 = (const float*)d_in[2];
    const float* R2 = (const float*)d_in[3];
    const float* R3 = (const float*)d_in[4];
    const float* f1 = (const float*)d_in[5];
    const float* f2 = (const float*)d_in[6];
    const float* f3 = (const float*)d_in[7];
    const float* u1 = (const float*)d_in[8];
    const float* u2 = (const float*)d_in[9];
    const float* u3 = (const float*)d_in[10];
    const int*  eix = (const int*)d_in[11];
    const float* W1 = (const float*)d_in[12];
    const float* b1 = (const float*)d_in[13];
    const float* W2 = (const float*)d_in[14];
    const float* b2 = (const float*)d_in[15];
    const float* Wr = (const float*)d_in[16];
    const float* br = (const float*)d_in[17];

    char* ws = (char*)d_ws;
    size_t off = 0;
    auto alloc = [&](size_t bytes) -> void* {
        void* p = ws + off;
        off = (off + bytes + 255) & ~(size_t)255;
        return p;
    };
    int* cnt       = (int*)alloc((size_t)N_NODES * 4);
    int* cursor    = (int*)alloc((size_t)N_NODES * 4);
    int* nb        = (int*)alloc((size_t)N_NODES * 4);
    int* tile_node = (int*)alloc((size_t)MAXT * 4);
    int* ntiles    = (int*)alloc(4);
    char* rec            = (char*)alloc((size_t)NSLOT * 128);
    unsigned short* vbf2 = (unsigned short*)alloc((size_t)N_NODES * 128 * 4 * 2);
    unsigned short* phi2 = (unsigned short*)alloc((size_t)N_NODES * 1024 * 2);
    unsigned short* W1T  = (unsigned short*)alloc(128 * 128 * 2);
    unsigned short* W2T  = (unsigned short*)alloc(1024 * 128 * 2);
    unsigned short* WrT  = (unsigned short*)alloc(1024 * 32 * 2);
    (void)ws_size; (void)in_sizes; (void)n_in; (void)out_size;

    float* out0 = (float*)d_out;
    float* out1 = out0 + (size_t)N_NODES * 128;

    hipMemsetAsync(cnt, 0, (size_t)N_NODES * 4, stream);
    init_kernel<<<5000, 256, 0, stream>>>(s, v, eix, W1, W2, Wr,
                                          out0, out1, vbf2, cnt, W1T, W2T, WrT);
    scan_phi_kernel<<<PHI_BLOCKS + 1, 256, 0, stream>>>(
        cnt, cursor, nb, tile_node, ntiles, s, W1T, b1, W2T, b2, phi2);
    rc_pad_kernel<<<RC_BLOCKS + PAD_BLOCKS, 256, 0, stream>>>(
        R1, R2, R3, f1, f2, f3, u1, u2, u3, eix, cnt, nb, cursor, rec);
    msg_kernel<<<MSG_GRID, 512, 0, stream>>>(rec, phi2, vbf2, WrT, br,
                                             tile_node, ntiles, out0, out1);
}

// Round 13
// 319.579 us; speedup vs baseline: 1.3815x; 1.0157x over previous
//
#include <hip/hip_runtime.h>

#define N_NODES 10000
#define N_EDGES 160000
#define MAXT     19400              // >= sum(ceil(deg/16)) <= (E + 15N)/16 = 19375
#define NSLOT    (MAXT * 16 + 16)   // 16-aligned CSR slots + guard
#define MSG_GRID 5000               // x4 strided tiles = 20000 slots
#define PHI_BLOCKS 628
#define RC_BLOCKS 5000              // E*8 / 256
#define PAD_BLOCKS 625              // N*16 / 256

typedef __attribute__((ext_vector_type(8))) __bf16 bf16x8;
typedef __attribute__((ext_vector_type(8))) unsigned short u16x8;
typedef __attribute__((ext_vector_type(4))) float f32x4;

static __device__ __forceinline__ unsigned short f2bf(float x) {
    union { float f; unsigned u; } un;
    un.f = x;
    unsigned r = un.u + 0x7fffu + ((un.u >> 16) & 1u);  // RNE
    return (unsigned short)(r >> 16);
}

static __device__ __forceinline__ float bf2f(unsigned short h) {
    union { unsigned u; float f; } un;
    un.u = ((unsigned)h) << 16;
    return un.f;
}

// ---------------------------------------------------------------------------
// Fused init: float4 copies, weight transpose->bf16, vbf2 packing, degree
// histogram. Grid = 5000x256.
// ---------------------------------------------------------------------------
__global__ __launch_bounds__(256) void init_kernel(
    const float* __restrict__ s, const float* __restrict__ v,
    const int* __restrict__ eix,
    const float* __restrict__ W1, const float* __restrict__ W2,
    const float* __restrict__ Wr,
    float* __restrict__ out0, float* __restrict__ out1,
    unsigned short* __restrict__ vbf2, int* __restrict__ cnt,
    unsigned short* __restrict__ W1T, unsigned short* __restrict__ W2T,
    unsigned short* __restrict__ WrT)
{
    int tid = blockIdx.x * 256 + threadIdx.x;
    if (tid < N_NODES * 96)                      // out1 = v, float4
        reinterpret_cast<float4*>(out1)[tid] = reinterpret_cast<const float4*>(v)[tid];
    if (tid < N_NODES * 32)                      // out0 = s, float4
        reinterpret_cast<float4*>(out0)[tid] = reinterpret_cast<const float4*>(s)[tid];
    if (tid < N_NODES * 128) {                   // vbf2[n][f] = {vx,vy,vz,0} bf16
        int n = tid >> 7, f = tid & 127;
        ushort4 q;
        q.x = f2bf(v[(size_t)n * 384 + f]);
        q.y = f2bf(v[(size_t)n * 384 + 128 + f]);
        q.z = f2bf(v[(size_t)n * 384 + 256 + f]);
        q.w = 0;
        *reinterpret_cast<ushort4*>(vbf2 + (size_t)tid * 4) = q;
    }
    if (tid < 131072) {                          // W2T [1024][128]
        int n = tid >> 7, k = tid & 127;
        W2T[tid] = f2bf(W2[k * 1024 + n]);
    }
    if (tid < 16384) {                           // W1T [128][128]
        int n = tid >> 7, k = tid & 127;
        W1T[tid] = f2bf(W1[k * 128 + n]);
    }
    if (tid < 32768) {                           // WrT [1024][32]
        int n = tid >> 5, k = tid & 31;
        WrT[tid] = f2bf(Wr[k * 1024 + n]);
    }
    if (tid < N_EDGES) atomicAdd(&cnt[eix[tid]], 1);
}

// ---------------------------------------------------------------------------
// Fused scan + phi. Blocks [0, PHI_BLOCKS) = phi (independent of scan);
// block PHI_BLOCKS = single-block scan (40 nodes/thread, one shfl pass) that
// hides entirely under phi.
// ---------------------------------------------------------------------------
__global__ __launch_bounds__(256) void scan_phi_kernel(
    const int* __restrict__ cnt, int* __restrict__ cursor,
    int* __restrict__ nb, int* __restrict__ tile_node,
    int* __restrict__ ntiles,
    const float* __restrict__ s, const unsigned short* __restrict__ W1T,
    const float* __restrict__ b1, const unsigned short* __restrict__ W2T,
    const float* __restrict__ b2, unsigned short* __restrict__ phi2)
{
    __shared__ unsigned short h_lds[64][136];
    __shared__ int ws4[4];
    int bx = blockIdx.x;
    int t = threadIdx.x, lane = t & 63, w = t >> 6;

    if (bx == PHI_BLOCKS) {
        // ---------------- scan: 256 threads x 40 nodes ----------------
        int n0 = t * 40;
        int sum = 0;
        for (int i = 0; i < 40; ++i) {
            int n = n0 + i;
            if (n < N_NODES) sum += (cnt[n] + 15) >> 4;
        }
        int x = sum;
        #pragma unroll
        for (int o = 1; o < 64; o <<= 1) {
            int y = __shfl_up(x, o);
            if (lane >= o) x += y;
        }
        if (lane == 63) ws4[w] = x;
        __syncthreads();
        if (t < 4) {
            int vsum = ws4[t];
            #pragma unroll
            for (int o = 1; o < 4; o <<= 1) {
                int y = __shfl_up(vsum, o);
                if (lane >= o) vsum += y;
            }
            ws4[t] = vsum;               // inclusive wave sums
        }
        __syncthreads();
        int wb = w ? ws4[w - 1] : 0;
        int run = wb + x - sum;          // exclusive prefix, tile units
        for (int i = 0; i < 40; ++i) {
            int n = n0 + i;
            if (n >= N_NODES) break;
            int tc = (cnt[n] + 15) >> 4;
            nb[n] = run * 16;
            cursor[n] = run * 16;
            for (int k = 0; k < tc; ++k) tile_node[run + k] = n;
            run += tc;
        }
        if (t == 255) *ntiles = run;
        return;
    }

    // ---------------- phi: silu(s@W1+b1)@W2+b2 ----------------
    int quad = lane >> 4, l16 = lane & 15;
    int m0 = (bx >> 2) * 64;
    int colg = bx & 3;

    int arow = m0 + w * 16 + l16;
    if (arow > N_NODES - 1) arow = N_NODES - 1;
    bf16x8 afr[4];
    #pragma unroll
    for (int ks = 0; ks < 4; ++ks) {
        const float* sp = s + (size_t)arow * 128 + ks * 32 + quad * 8;
        #pragma unroll
        for (int jj = 0; jj < 8; ++jj) afr[ks][jj] = (__bf16)sp[jj];
    }
    #pragma unroll
    for (int cg = 0; cg < 8; ++cg) {
        int col = cg * 16 + l16;
        f32x4 acc = {0.f, 0.f, 0.f, 0.f};
        #pragma unroll
        for (int ks = 0; ks < 4; ++ks) {
            bf16x8 bf = *reinterpret_cast<const bf16x8*>(W1T + (size_t)col * 128 + ks * 32 + quad * 8);
            acc = __builtin_amdgcn_mfma_f32_16x16x32_bf16(afr[ks], bf, acc, 0, 0, 0);
        }
        float bb = b1[col];
        #pragma unroll
        for (int r = 0; r < 4; ++r) {
            int row = w * 16 + quad * 4 + r;
            float val = acc[r] + bb;
            h_lds[row][col] = f2bf(val / (1.f + __expf(-val)));
        }
    }
    __syncthreads();

    bf16x8 a2[4][4];
    #pragma unroll
    for (int rg = 0; rg < 4; ++rg)
        #pragma unroll
        for (int ks = 0; ks < 4; ++ks)
            a2[rg][ks] = *reinterpret_cast<const bf16x8*>(&h_lds[rg * 16 + l16][ks * 32 + quad * 8]);
    #pragma unroll
    for (int i = 0; i < 4; ++i) {
        int col = colg * 256 + w * 64 + i * 16 + l16;
        f32x4 acc2[4] = {{0,0,0,0},{0,0,0,0},{0,0,0,0},{0,0,0,0}};
        #pragma unroll
        for (int ks = 0; ks < 4; ++ks) {
            bf16x8 bf = *reinterpret_cast<const bf16x8*>(W2T + (size_t)col * 128 + ks * 32 + quad * 8);
            #pragma unroll
            for (int rg = 0; rg < 4; ++rg)
                acc2[rg] = __builtin_amdgcn_mfma_f32_16x16x32_bf16(a2[rg][ks], bf, acc2[rg], 0, 0, 0);
        }
        float bb = b2[col];
        int f = col & 127, cc = col >> 7;
        #pragma unroll
        for (int rg = 0; rg < 4; ++rg)
            #pragma unroll
            for (int r = 0; r < 4; ++r) {
                int row = m0 + rg * 16 + quad * 4 + r;
                if (row < N_NODES)
                    phi2[(size_t)row * 1024 + f * 8 + cc] = f2bf(acc2[rg][r] + bb);
            }
    }
}

// ---------------------------------------------------------------------------
// rc + pad on the 128-B interleaved record: rec[slot] = {Rc 32xushort | hdr
// 16xfloat}. Per edge ONE contiguous 128B line.
//  blocks [0, RC_BLOCKS):      per-edge Rc/hdr at CSR slot
//  blocks [RC_BLOCKS, +PAD):   zero pad slots
// ---------------------------------------------------------------------------
__global__ __launch_bounds__(256) void rc_pad_kernel(
    const float* __restrict__ R1, const float* __restrict__ R2,
    const float* __restrict__ R3,
    const float* __restrict__ f1, const float* __restrict__ f2,
    const float* __restrict__ f3,
    const float* __restrict__ u1, const float* __restrict__ u2,
    const float* __restrict__ u3,
    const int* __restrict__ eix, const int* __restrict__ cnt,
    const int* __restrict__ nb, int* __restrict__ cursor,
    char* __restrict__ rec)
{
    int bx = blockIdx.x;
    if (bx >= RC_BLOCKS) {
        // ---------------- pad: zero unused slots (full 128B record) -------
        int t2 = (bx - RC_BLOCKS) * 256 + threadIdx.x;   // [0, 16N)
        int n = t2 >> 4, r = t2 & 15;
        int deg = cnt[n], tc = (deg + 15) >> 4;
        int p = deg + r;
        if (p < tc * 16) {
            size_t slot = (size_t)nb[n] + p;
            f32x4 z = {0.f, 0.f, 0.f, 0.f};
            f32x4* rp = reinterpret_cast<f32x4*>(rec + slot * 128);
            #pragma unroll
            for (int q = 0; q < 8; ++q) rp[q] = z;
        }
        return;
    }

    // ---------------- rc: Rc + packed header at CSR slot ----------------
    int tid = bx * 256 + threadIdx.x;            // exactly E*8 threads
    int e = tid >> 3, sub = tid & 7;
    int lane = threadIdx.x & 63;
    float a = f1[e], b = f2[e], c = f3[e];
    int k0 = sub * 4;
    float4 r1 = *reinterpret_cast<const float4*>(R1 + (size_t)e * 32 + k0);
    float4 r2 = *reinterpret_cast<const float4*>(R2 + (size_t)e * 32 + k0);
    float4 r3 = *reinterpret_cast<const float4*>(R3 + (size_t)e * 32 + k0);
    ushort4 o;
    o.x = f2bf(r1.x * a + r2.x * b + r3.x * c);
    o.y = f2bf(r1.y * a + r2.y * b + r3.y * c);
    o.z = f2bf(r1.z * a + r2.z * b + r3.z * c);
    o.w = f2bf(r1.w * a + r2.w * b + r3.w * c);
    int slot = 0;
    if (sub == 0) slot = atomicAdd(&cursor[eix[e]], 1);
    slot = __shfl(slot, lane & 56);              // broadcast from sub0
    *reinterpret_cast<ushort4*>(rec + (size_t)slot * 128 + k0 * 2) = o;
    float* hf = reinterpret_cast<float*>(rec + (size_t)slot * 128 + 64);
    if (sub == 0) {
        float4 h;
        h.x = __int_as_float(eix[N_EDGES + e]);  // j
        h.y = a + b + c;                         // fsum
        h.z = 0.f; h.w = 0.f;
        *reinterpret_cast<float4*>(hf) = h;
    } else if (sub < 4) {
        const float* up = (sub == 1 ? u1 : (sub == 2 ? u2 : u3)) + (size_t)e * 3;
        float4 h;
        h.x = up[0]; h.y = up[1]; h.z = up[2]; h.w = 0.f;
        *reinterpret_cast<float4*>(hf + sub * 4) = h;
    }
}

// ---------------------------------------------------------------------------
// Main msg kernel: the converged optimum (r6). Double-buffer pipeline on the
// 128B record; srow stride 20 (16B-aligned vector LDS reads, 2-way conflicts
// only); direct-cross epilogue (64 arch VGPR + 32 acc = 96 unified -> 4
// waves/SIMD, the max occupancy band this state fits). Plain loads: rec lines
// are touched twice (Rc bytes [0,64) + hdr bytes [64,128)) so nt eviction
// hurts (r12: +3MB FETCH, +3us).
// ---------------------------------------------------------------------------
__global__ __launch_bounds__(512) void msg_kernel(
    const char* __restrict__ rec,
    const unsigned short* __restrict__ phi2, const unsigned short* __restrict__ vbf2,
    const unsigned short* __restrict__ WrT, const float* __restrict__ br,
    const int* __restrict__ tile_node, const int* __restrict__ ntiles,
    float* __restrict__ out0, float* __restrict__ out1)
{
    int t = threadIdx.x, lane = t & 63, w = t >> 6;
    int quad = lane >> 4, l16 = lane & 15;
    int fcol = w * 16 + l16;
    const int nt = *ntiles;
    const float* recf = reinterpret_cast<const float*>(rec);

    bf16x8 bfrag[8];
    float brv[8];
    #pragma unroll
    for (int c = 0; c < 8; ++c) {
        int col = c * 128 + fcol;
        bfrag[c] = *reinterpret_cast<const bf16x8*>(WrT + (size_t)col * 32 + quad * 8);
        brv[c] = br[col];
    }

    __shared__ __align__(16) float srow[2][16][20];  // [j,fs,-,-|u1 -,|u2 -,|u3 -,pad]

    int tile = blockIdx.x;
    bf16x8 af;
    if (tile < nt) {
        if (t < 256)
            srow[0][t >> 4][t & 15] = recf[((size_t)tile * 16 + (t >> 4)) * 32 + 16 + (t & 15)];
        af = *reinterpret_cast<const bf16x8*>(rec + ((size_t)tile * 16 + l16) * 128 + quad * 16);
    }

    for (int k = 0; tile < nt; ++k, tile += MSG_GRID) {
        int p = k & 1;
        __syncthreads();   // publishes srow[p]; reads of srow[p^1] all done

        f32x4 acc[8];
        #pragma unroll
        for (int c = 0; c < 8; ++c) {
            f32x4 z = {0.f, 0.f, 0.f, 0.f};
            acc[c] = __builtin_amdgcn_mfma_f32_16x16x32_bf16(af, bfrag[c], z, 0, 0, 0);
        }

        // stage NEXT tile (header -> srow[p^1], A-frag -> af) under the epilogue
        int tn = tile + MSG_GRID;
        if (tn < nt) {
            if (t < 256)
                srow[p ^ 1][t >> 4][t & 15] = recf[((size_t)tn * 16 + (t >> 4)) * 32 + 16 + (t & 15)];
            af = *reinterpret_cast<const bf16x8*>(rec + ((size_t)tn * 16 + l16) * 128 + quad * 16);
        }

        float ds = 0.f, d0 = 0.f, d1 = 0.f, d2 = 0.f;
        #pragma unroll
        for (int r = 0; r < 4; ++r) {
            const float* rw = srow[p][quad * 4 + r];
            float2 jf = *reinterpret_cast<const float2*>(rw);
            f32x4 U1 = *reinterpret_cast<const f32x4*>(rw + 4);
            f32x4 U2 = *reinterpret_cast<const f32x4*>(rw + 8);
            f32x4 U3 = *reinterpret_cast<const f32x4*>(rw + 12);
            int j = __float_as_int(jf.x);
            float fs = jf.y;
            size_t o = (size_t)j * 128 + fcol;
            u16x8 ph = *reinterpret_cast<const u16x8*>(phi2 + o * 8);
            ushort4 vb = *reinterpret_cast<const ushort4*>(vbf2 + o * 4);
            float x[8];
            #pragma unroll
            for (int c = 0; c < 8; ++c)
                x[c] = bf2f(ph[c]) * (acc[c][r] + brv[c] * fs);
            float vjx = bf2f(vb.x), vjy = bf2f(vb.y), vjz = bf2f(vb.z);

            ds += x[0];
            d0 += vjx * x[1] + U1.x * x[2] + U2.x * x[3] + U3.x * x[4]
                + x[5] * (vjy * U1.z - vjz * U1.y)
                + x[6] * (vjy * U2.z - vjz * U2.y)
                + x[7] * (vjy * U3.z - vjz * U3.y);
            d1 += vjy * x[1] + U1.y * x[2] + U2.y * x[3] + U3.y * x[4]
                + x[5] * (vjz * U1.x - vjx * U1.z)
                + x[6] * (vjz * U2.x - vjx * U2.z)
                + x[7] * (vjz * U3.x - vjx * U3.z);
            d2 += vjz * x[1] + U1.z * x[2] + U2.z * x[3] + U3.z * x[4]
                + x[5] * (vjx * U1.y - vjy * U1.x)
                + x[6] * (vjx * U2.y - vjy * U2.x)
                + x[7] * (vjx * U3.y - vjy * U3.x);
        }

        ds += __shfl_xor(ds, 16); ds += __shfl_xor(ds, 32);
        d0 += __shfl_xor(d0, 16); d0 += __shfl_xor(d0, 32);
        d1 += __shfl_xor(d1, 16); d1 += __shfl_xor(d1, 32);
        d2 += __shfl_xor(d2, 16); d2 += __shfl_xor(d2, 32);

        if (quad == 0) {
            int node = tile_node[tile];
            atomicAdd(&out0[(size_t)node * 128 + fcol], ds);
            size_t vo = (size_t)node * 384 + fcol;
            atomicAdd(&out1[vo], d0);
            atomicAdd(&out1[vo + 128], d1);
            atomicAdd(&out1[vo + 256], d2);
        }
    }
}

// ---------------------------------------------------------------------------
extern "C" void kernel_launch(void* const* d_in, const int* in_sizes, int n_in,
                              void* d_out, int out_size, void* d_ws, size_t ws_size,
                              hipStream_t stream) {
    const float* s  = (const float*)d_in[0];
    const float* v  = (const float*)d_in[1];
    const float* R1 = (const float*)d_in[2];
    const float* R2 = (const float*)d_in[3];
    const float* R3 = (const float*)d_in[4];
    const float* f1 = (const float*)d_in[5];
    const float* f2 = (const float*)d_in[6];
    const float* f3 = (const float*)d_in[7];
    const float* u1 = (const float*)d_in[8];
    const float* u2 = (const float*)d_in[9];
    const float* u3 = (const float*)d_in[10];
    const int*  eix = (const int*)d_in[11];
    const float* W1 = (const float*)d_in[12];
    const float* b1 = (const float*)d_in[13];
    const float* W2 = (const float*)d_in[14];
    const float* b2 = (const float*)d_in[15];
    const float* Wr = (const float*)d_in[16];
    const float* br = (const float*)d_in[17];

    char* ws = (char*)d_ws;
    size_t off = 0;
    auto alloc = [&](size_t bytes) -> void* {
        void* p = ws + off;
        off = (off + bytes + 255) & ~(size_t)255;
        return p;
    };
    int* cnt       = (int*)alloc((size_t)N_NODES * 4);
    int* cursor    = (int*)alloc((size_t)N_NODES * 4);
    int* nb        = (int*)alloc((size_t)N_NODES * 4);
    int* tile_node = (int*)alloc((size_t)MAXT * 4);
    int* ntiles    = (int*)alloc(4);
    char* rec            = (char*)alloc((size_t)NSLOT * 128);
    unsigned short* vbf2 = (unsigned short*)alloc((size_t)N_NODES * 128 * 4 * 2);
    unsigned short* phi2 = (unsigned short*)alloc((size_t)N_NODES * 1024 * 2);
    unsigned short* W1T  = (unsigned short*)alloc(128 * 128 * 2);
    unsigned short* W2T  = (unsigned short*)alloc(1024 * 128 * 2);
    unsigned short* WrT  = (unsigned short*)alloc(1024 * 32 * 2);
    (void)ws_size; (void)in_sizes; (void)n_in; (void)out_size;

    float* out0 = (float*)d_out;
    float* out1 = out0 + (size_t)N_NODES * 128;

    hipMemsetAsync(cnt, 0, (size_t)N_NODES * 4, stream);
    init_kernel<<<5000, 256, 0, stream>>>(s, v, eix, W1, W2, Wr,
                                          out0, out1, vbf2, cnt, W1T, W2T, WrT);
    scan_phi_kernel<<<PHI_BLOCKS + 1, 256, 0, stream>>>(
        cnt, cursor, nb, tile_node, ntiles, s, W1T, b1, W2T, b2, phi2);
    rc_pad_kernel<<<RC_BLOCKS + PAD_BLOCKS, 256, 0, stream>>>(
        R1, R2, R3, f1, f2, f3, u1, u2, u3, eix, cnt, nb, cursor, rec);
    msg_kernel<<<MSG_GRID, 512, 0, stream>>>(rec, phi2, vbf2, WrT, br,
                                             tile_node, ntiles, out0, out1);
}